// Round 1
// baseline (2735.004 us; speedup 1.0000x reference)
//
#include <hip/hip_runtime.h>
#include <math.h>

#define N_NODES 8000
#define N_EDGES 64000
#define ETOT    (N_EDGES + N_NODES)   // 72000, self-loops appended
#define EDIM    16
#define NGRAPHS 64

// ---------------- CSR build ----------------

__global__ void count_deg(const int* __restrict__ dst0, int* __restrict__ deg) {
    int e = blockIdx.x * 256 + threadIdx.x;
    if (e < N_EDGES) atomicAdd(&deg[dst0[e]], 1);
}

// single-block inclusive scan over 8000 degrees (+1 self-loop each) -> rowptr
__global__ void scan_deg(const int* __restrict__ deg, int* __restrict__ rowptr) {
    __shared__ int sh[256];
    __shared__ int carry_s;
    int t = threadIdx.x;
    if (t == 0) { carry_s = 0; rowptr[0] = 0; }
    __syncthreads();
    for (int base = 0; base < N_NODES; base += 256) {
        int i = base + t;
        int v = (i < N_NODES) ? (deg[i] + 1) : 0;   // +1 self loop
        sh[t] = v;
        __syncthreads();
        for (int off = 1; off < 256; off <<= 1) {
            int u = (t >= off) ? sh[t - off] : 0;
            __syncthreads();
            sh[t] += u;
            __syncthreads();
        }
        int incl = sh[t] + carry_s;
        if (i < N_NODES) rowptr[i + 1] = incl;
        __syncthreads();
        if (t == 255) carry_s = incl;
        __syncthreads();
    }
}

__global__ void copy_off(const int* __restrict__ rowptr, int* __restrict__ woff) {
    int i = blockIdx.x * 256 + threadIdx.x;
    if (i < N_NODES) woff[i] = rowptr[i];
}

__global__ void fill_eid(const int* __restrict__ dst0, int* __restrict__ woff,
                         int* __restrict__ eid) {
    int i = blockIdx.x * 256 + threadIdx.x;
    if (i < N_EDGES) {
        int pos = atomicAdd(&woff[dst0[i]], 1);
        eid[pos] = i;
    } else if (i < ETOT) {
        int n = i - N_EDGES;
        int pos = atomicAdd(&woff[n], 1);
        eid[pos] = i;  // encodes self-loop at node n
    }
}

// per-dst mean of incoming edge_attr (fill_value='mean'); isolated node -> 0
__global__ void ea_loop_kernel(const int* __restrict__ rowptr, const int* __restrict__ eid,
                               const float* __restrict__ edge_attr, float* __restrict__ ea_loop) {
    int n = blockIdx.x * 256 + threadIdx.x;
    if (n >= N_NODES) return;
    float s[EDIM];
#pragma unroll
    for (int k = 0; k < EDIM; k++) s[k] = 0.f;
    int cnt = 0;
    int b = rowptr[n], t = rowptr[n + 1];
    for (int i = b; i < t; i++) {
        int e = eid[i];
        if (e < N_EDGES) {
            cnt++;
            const float* ea = edge_attr + (size_t)e * EDIM;
#pragma unroll
            for (int k = 0; k < EDIM; k++) s[k] += ea[k];
        }
    }
    float inv = 1.f / (float)(cnt > 0 ? cnt : 1);
#pragma unroll
    for (int k = 0; k < EDIM; k++) ea_loop[(size_t)n * EDIM + k] = s[k] * inv;
}

// ---------------- fp32 GEMM: C[M,Nc] = A[M,K] @ B[K,Nc] + bias ----------------
// BM=BN=128, BK=16, 256 threads, 8x8 microtile. Nc,K multiples of 16; M guarded.

__global__ __launch_bounds__(256) void gemm_bias(
        const float* __restrict__ A, const float* __restrict__ B,
        const float* __restrict__ bias, float* __restrict__ C,
        int M, int K, int Nc) {
    __shared__ float As[16][132];
    __shared__ float Bs[16][128];
    int t = threadIdx.x;
    int m0 = blockIdx.y * 128, n0 = blockIdx.x * 128;
    int tm = (t >> 4) * 8, tn = (t & 15) * 8;
    float acc[8][8] = {};
    for (int k0 = 0; k0 < K; k0 += 16) {
#pragma unroll
        for (int r = 0; r < 2; r++) {
            int f = t + r * 256;          // 512 float4 in A tile
            int m = f >> 2, k4 = (f & 3) * 4;
            float4 v = make_float4(0.f, 0.f, 0.f, 0.f);
            if (m0 + m < M) v = *(const float4*)(A + (size_t)(m0 + m) * K + k0 + k4);
            As[k4 + 0][m] = v.x; As[k4 + 1][m] = v.y;
            As[k4 + 2][m] = v.z; As[k4 + 3][m] = v.w;
        }
#pragma unroll
        for (int r = 0; r < 2; r++) {
            int f = t + r * 256;          // 512 float4 in B tile
            int k = f >> 5, n4 = (f & 31) * 4;
            *(float4*)&Bs[k][n4] = *(const float4*)(B + (size_t)(k0 + k) * Nc + n0 + n4);
        }
        __syncthreads();
#pragma unroll
        for (int k = 0; k < 16; k++) {
            float a[8], b[8];
#pragma unroll
            for (int i = 0; i < 8; i++) a[i] = As[k][tm + i];
#pragma unroll
            for (int j = 0; j < 8; j++) b[j] = Bs[k][tn + j];
#pragma unroll
            for (int i = 0; i < 8; i++)
#pragma unroll
                for (int j = 0; j < 8; j++) acc[i][j] += a[i] * b[j];
        }
        __syncthreads();
    }
#pragma unroll
    for (int i = 0; i < 8; i++) {
        int m = m0 + tm + i;
        if (m < M) {
#pragma unroll
            for (int j = 0; j < 8; j++)
                C[(size_t)m * Nc + n0 + tn + j] = acc[i][j] + bias[n0 + tn + j];
        }
    }
}

// ---------------- edge logits (fused edge embedding) ----------------
// one wave per edge; chunk of 64 channels lies inside one head (co % 64 == 0)

__global__ __launch_bounds__(256) void edge_logits(
        const float* __restrict__ xl, const float* __restrict__ xr,
        const float* __restrict__ We, const float* __restrict__ att,
        const float* __restrict__ edge_attr, const float* __restrict__ ea_loop,
        const int* __restrict__ src0, const int* __restrict__ dst0,
        float* __restrict__ logits, int H, int co) {
    int hc = H * co;
    int wave = threadIdx.x >> 6, lane = threadIdx.x & 63;
    int e = blockIdx.x * 4 + wave;
    if (e >= ETOT) return;
    int s, d;
    const float* ea;
    if (e < N_EDGES) { s = src0[e]; d = dst0[e]; ea = edge_attr + (size_t)e * EDIM; }
    else             { s = e - N_EDGES; d = s;   ea = ea_loop + (size_t)s * EDIM; }
    float ear[EDIM];
#pragma unroll
    for (int k = 0; k < EDIM; k++) ear[k] = ea[k];
    const float* xls = xl + (size_t)s * hc;
    const float* xrd = xr + (size_t)d * hc;
    float accH[3] = {0.f, 0.f, 0.f};
    for (int c0 = 0; c0 < hc; c0 += 64) {
        int j = c0 + lane;
        float eev = 0.f;
#pragma unroll
        for (int k = 0; k < EDIM; k++) eev += ear[k] * We[k * hc + j];
        float m = xls[j] + xrd[j] + eev;
        m = (m > 0.f) ? m : 0.2f * m;           // leaky_relu, slope 0.2
        float contrib = m * att[j];             // att flat is [h*co + c] == j
        int hh = c0 / co;                       // wave-uniform
        if (hh == 0) accH[0] += contrib;
        else if (hh == 1) accH[1] += contrib;
        else accH[2] += contrib;
    }
#pragma unroll
    for (int off = 32; off > 0; off >>= 1) {
        accH[0] += __shfl_down(accH[0], off);
        accH[1] += __shfl_down(accH[1], off);
        accH[2] += __shfl_down(accH[2], off);
    }
    if (lane == 0) {
        for (int h = 0; h < H; h++) logits[(size_t)e * H + h] = accH[h];
    }
}

// ---------------- segmented softmax over incoming edges, in-place ----------------

__global__ void seg_softmax(const int* __restrict__ rowptr, const int* __restrict__ eid,
                            float* __restrict__ logits, int H) {
    int tid = blockIdx.x * 256 + threadIdx.x;
    if (tid >= N_NODES * H) return;
    int n = tid / H, h = tid - n * H;
    int b = rowptr[n], t = rowptr[n + 1];
    float mx = -1e30f;
    for (int i = b; i < t; i++) {
        float v = logits[(size_t)eid[i] * H + h];
        mx = fmaxf(mx, v);
    }
    float ssum = 0.f;
    for (int i = b; i < t; i++)
        ssum += expf(logits[(size_t)eid[i] * H + h] - mx);
    float inv = 1.f / ssum;   // self-loop guarantees ssum > 0
    for (int i = b; i < t; i++) {
        size_t idx = (size_t)eid[i] * H + h;
        logits[idx] = expf(logits[idx] - mx) * inv;
    }
}

// ---------------- aggregation: out[n,j] = relu(sum_e alpha[e,h]*xl[src,j] + bias[j]) ----

__global__ __launch_bounds__(256) void aggregate(
        const int* __restrict__ rowptr, const int* __restrict__ eid,
        const int* __restrict__ src0, const float* __restrict__ alpha,
        const float* __restrict__ xl, const float* __restrict__ bias,
        float* __restrict__ out, int H, int co) {
    int hc = H * co;
    int n = blockIdx.x;
    int b = rowptr[n], t = rowptr[n + 1];
    for (int j = threadIdx.x; j < hc; j += 256) {
        int h = j / co;
        float acc = 0.f;
        for (int i = b; i < t; i++) {
            int e = eid[i];
            int s = (e < N_EDGES) ? src0[e] : (e - N_EDGES);
            acc += alpha[(size_t)e * H + h] * xl[(size_t)s * hc + j];
        }
        acc += bias[j];
        out[(size_t)n * hc + j] = fmaxf(acc, 0.f);
    }
}

// ---------------- pooling + MLP head ----------------

__global__ void pool_cnt(const int* __restrict__ batch, int* __restrict__ gcnt) {
    int n = blockIdx.x * 256 + threadIdx.x;
    if (n < N_NODES) atomicAdd(&gcnt[batch[n]], 1);
}

__global__ void pool_sum(const int* __restrict__ batch, const float* __restrict__ h,
                         float* __restrict__ pooled) {
    int tid = blockIdx.x * 256 + threadIdx.x;
    if (tid >= N_NODES * 256) return;
    int n = tid >> 8, c = tid & 255;
    atomicAdd(&pooled[batch[n] * 256 + c], h[tid]);
}

__global__ void mlp_head(const float* __restrict__ pooled, const int* __restrict__ gcnt,
                         const float* __restrict__ fc1w, const float* __restrict__ fc1b,
                         const float* __restrict__ fc2w, const float* __restrict__ fc2b,
                         float* __restrict__ out) {
    int g = threadIdx.x;
    if (g >= NGRAPHS) return;
    float inv = 1.f / (float)(gcnt[g] > 0 ? gcnt[g] : 1);
    float s[64];
#pragma unroll
    for (int j = 0; j < 64; j++) s[j] = fc1b[j];
    for (int c = 0; c < 256; c++) {
        float mv = pooled[g * 256 + c] * inv;
#pragma unroll
        for (int j = 0; j < 64; j++) s[j] += mv * fc1w[c * 64 + j];
    }
    float o = 0.f;
#pragma unroll
    for (int j = 0; j < 64; j++) o += fmaxf(s[j], 0.f) * fc2w[j];
    out[g] = o + fc2b[0];
}

// ---------------- launch ----------------

extern "C" void kernel_launch(void* const* d_in, const int* in_sizes, int n_in,
                              void* d_out, int out_size, void* d_ws, size_t ws_size,
                              hipStream_t stream) {
    const float* x         = (const float*)d_in[0];
    const int*   edge_index= (const int*)d_in[1];
    const float* edge_attr = (const float*)d_in[2];
    const int*   batch     = (const int*)d_in[3];
    const int* src0 = edge_index;
    const int* dst0 = edge_index + N_EDGES;

    const float *Wl[4], *bl[4], *Wr[4], *br[4], *We[4], *att[4], *bias[4];
    for (int i = 0; i < 4; i++) {
        int base = 4 + 7 * i;
        Wl[i]   = (const float*)d_in[base + 0];
        bl[i]   = (const float*)d_in[base + 1];
        Wr[i]   = (const float*)d_in[base + 2];
        br[i]   = (const float*)d_in[base + 3];
        We[i]   = (const float*)d_in[base + 4];
        att[i]  = (const float*)d_in[base + 5];
        bias[i] = (const float*)d_in[base + 6];
    }
    const float* fc1w = (const float*)d_in[32];
    const float* fc1b = (const float*)d_in[33];
    const float* fc2w = (const float*)d_in[34];
    const float* fc2b = (const float*)d_in[35];
    float* out = (float*)d_out;

    // workspace layout (word offsets, each region 256B-aligned)
    float* ws = (float*)d_ws;
    int*   rowptr  = (int*)(ws + 0);            // 8001 ints
    int*   woff    = (int*)(ws + 8064);         // 8000 ints (deg, then fill offsets)
    int*   eid     = (int*)(ws + 16128);        // 72000 ints
    float* ea_loop = ws + 88128;                // 8000*16
    float* logits  = ws + 216128;               // 72000*3 (overwritten by alpha)
    float* xl      = ws + 432128;               // 8000*1536
    float* xr      = xl  + 12288000;
    float* hb0     = xr  + 12288000;
    float* hb1     = hb0 + 12288000;
    float* pooled  = hb1 + 12288000;            // 64*256
    int*   gcnt    = (int*)(pooled + 16384);    // 64

    // CSR (layer-invariant, built once per call)
    hipMemsetAsync(woff, 0, N_NODES * sizeof(int), stream);
    count_deg<<<(N_EDGES + 255) / 256, 256, 0, stream>>>(dst0, woff);
    scan_deg<<<1, 256, 0, stream>>>(woff, rowptr);
    copy_off<<<(N_NODES + 255) / 256, 256, 0, stream>>>(rowptr, woff);
    fill_eid<<<(ETOT + 255) / 256, 256, 0, stream>>>(dst0, woff, eid);
    ea_loop_kernel<<<(N_NODES + 255) / 256, 256, 0, stream>>>(rowptr, eid, edge_attr, ea_loop);

    const int IN[4] = {256, 1536, 1024, 512};
    const int HH[4] = {3, 2, 2, 1};
    const int CO[4] = {512, 512, 256, 256};
    const float* hin = x;
    float* houts[4] = {hb0, hb1, hb0, hb1};

    for (int L = 0; L < 4; L++) {
        int K = IN[L], H = HH[L], co = CO[L], hc = H * co;
        dim3 gg(hc / 128, (N_NODES + 127) / 128);
        gemm_bias<<<gg, 256, 0, stream>>>(hin, Wl[L], bl[L], xl, N_NODES, K, hc);
        gemm_bias<<<gg, 256, 0, stream>>>(hin, Wr[L], br[L], xr, N_NODES, K, hc);
        edge_logits<<<(ETOT + 3) / 4, 256, 0, stream>>>(
            xl, xr, We[L], att[L], edge_attr, ea_loop, src0, dst0, logits, H, co);
        seg_softmax<<<(N_NODES * H + 255) / 256, 256, 0, stream>>>(rowptr, eid, logits, H);
        aggregate<<<N_NODES, 256, 0, stream>>>(
            rowptr, eid, src0, logits, xl, bias[L], houts[L], H, co);
        hin = houts[L];
    }

    hipMemsetAsync(pooled, 0, (16384 + 64) * sizeof(float), stream);
    pool_cnt<<<(N_NODES + 255) / 256, 256, 0, stream>>>(batch, gcnt);
    pool_sum<<<(N_NODES * 256 + 255) / 256, 256, 0, stream>>>(batch, hin, pooled);
    mlp_head<<<1, 64, 0, stream>>>(pooled, gcnt, fc1w, fc1b, fc2w, fc2b, out);
}

// Round 2
// 2191.612 us; speedup vs baseline: 1.2479x; 1.2479x over previous
//
#include <hip/hip_runtime.h>
#include <math.h>

#define N_NODES 8000
#define N_EDGES 64000
#define ETOT    (N_EDGES + N_NODES)   // 72000, self-loops appended
#define EDIM    16
#define NGRAPHS 64

// ---------------- CSR build ----------------

__global__ void count_deg(const int* __restrict__ dst0, int* __restrict__ deg) {
    int e = blockIdx.x * 256 + threadIdx.x;
    if (e < N_EDGES) atomicAdd(&deg[dst0[e]], 1);
}

__global__ void scan_deg(const int* __restrict__ deg, int* __restrict__ rowptr) {
    __shared__ int sh[256];
    __shared__ int carry_s;
    int t = threadIdx.x;
    if (t == 0) { carry_s = 0; rowptr[0] = 0; }
    __syncthreads();
    for (int base = 0; base < N_NODES; base += 256) {
        int i = base + t;
        int v = (i < N_NODES) ? (deg[i] + 1) : 0;   // +1 self loop
        sh[t] = v;
        __syncthreads();
        for (int off = 1; off < 256; off <<= 1) {
            int u = (t >= off) ? sh[t - off] : 0;
            __syncthreads();
            sh[t] += u;
            __syncthreads();
        }
        int incl = sh[t] + carry_s;
        if (i < N_NODES) rowptr[i + 1] = incl;
        __syncthreads();
        if (t == 255) carry_s = incl;
        __syncthreads();
    }
}

__global__ void copy_off(const int* __restrict__ rowptr, int* __restrict__ woff) {
    int i = blockIdx.x * 256 + threadIdx.x;
    if (i < N_NODES) woff[i] = rowptr[i];
}

__global__ void fill_eid(const int* __restrict__ dst0, int* __restrict__ woff,
                         int* __restrict__ eid) {
    int i = blockIdx.x * 256 + threadIdx.x;
    if (i < N_EDGES) {
        int pos = atomicAdd(&woff[dst0[i]], 1);
        eid[pos] = i;
    } else if (i < ETOT) {
        int n = i - N_EDGES;
        int pos = atomicAdd(&woff[n], 1);
        eid[pos] = i;
    }
}

__global__ void ea_loop_kernel(const int* __restrict__ rowptr, const int* __restrict__ eid,
                               const float* __restrict__ edge_attr, float* __restrict__ ea_loop) {
    int n = blockIdx.x * 256 + threadIdx.x;
    if (n >= N_NODES) return;
    float s[EDIM];
#pragma unroll
    for (int k = 0; k < EDIM; k++) s[k] = 0.f;
    int cnt = 0;
    int b = rowptr[n], t = rowptr[n + 1];
    for (int i = b; i < t; i++) {
        int e = eid[i];
        if (e < N_EDGES) {
            cnt++;
            const float* ea = edge_attr + (size_t)e * EDIM;
#pragma unroll
            for (int k = 0; k < EDIM; k++) s[k] += ea[k];
        }
    }
    float inv = 1.f / (float)(cnt > 0 ? cnt : 1);
#pragma unroll
    for (int k = 0; k < EDIM; k++) ea_loop[(size_t)n * EDIM + k] = s[k] * inv;
}

// ---------------- fp32 GEMM: C[M,Nc] = A[M,K] @ B[K,Nc] + bias ----------------

__global__ __launch_bounds__(256) void gemm_bias(
        const float* __restrict__ A, const float* __restrict__ B,
        const float* __restrict__ bias, float* __restrict__ C,
        int M, int K, int Nc) {
    __shared__ float As[16][132];
    __shared__ float Bs[16][128];
    int t = threadIdx.x;
    int m0 = blockIdx.y * 128, n0 = blockIdx.x * 128;
    int tm = (t >> 4) * 8, tn = (t & 15) * 8;
    float acc[8][8] = {};
    for (int k0 = 0; k0 < K; k0 += 16) {
#pragma unroll
        for (int r = 0; r < 2; r++) {
            int f = t + r * 256;
            int m = f >> 2, k4 = (f & 3) * 4;
            float4 v = make_float4(0.f, 0.f, 0.f, 0.f);
            if (m0 + m < M) v = *(const float4*)(A + (size_t)(m0 + m) * K + k0 + k4);
            As[k4 + 0][m] = v.x; As[k4 + 1][m] = v.y;
            As[k4 + 2][m] = v.z; As[k4 + 3][m] = v.w;
        }
#pragma unroll
        for (int r = 0; r < 2; r++) {
            int f = t + r * 256;
            int k = f >> 5, n4 = (f & 31) * 4;
            *(float4*)&Bs[k][n4] = *(const float4*)(B + (size_t)(k0 + k) * Nc + n0 + n4);
        }
        __syncthreads();
#pragma unroll
        for (int k = 0; k < 16; k++) {
            float a[8], b[8];
#pragma unroll
            for (int i = 0; i < 8; i++) a[i] = As[k][tm + i];
#pragma unroll
            for (int j = 0; j < 8; j++) b[j] = Bs[k][tn + j];
#pragma unroll
            for (int i = 0; i < 8; i++)
#pragma unroll
                for (int j = 0; j < 8; j++) acc[i][j] += a[i] * b[j];
        }
        __syncthreads();
    }
#pragma unroll
    for (int i = 0; i < 8; i++) {
        int m = m0 + tm + i;
        if (m < M) {
#pragma unroll
            for (int j = 0; j < 8; j++)
                C[(size_t)m * Nc + n0 + tn + j] = acc[i][j] + bias[n0 + tn + j];
        }
    }
}

// ---------------- edge logits v2 ----------------
// grid = (edge_groups of 128, hc/256 chunks), block = 256 (4 waves).
// Each wave owns the block's 256-channel chunk with We sub-tile in REGISTERS
// (16 x float4 per lane), processes 32 edges. ea/src/dst staged in LDS.
// Per (edge, chunk): wave-reduce partial head logit -> atomicAdd.

__global__ __launch_bounds__(256) void edge_logits2(
        const float* __restrict__ xl, const float* __restrict__ xr,
        const float* __restrict__ We, const float* __restrict__ att,
        const float* __restrict__ edge_attr, const float* __restrict__ ea_loop,
        const int* __restrict__ src0, const int* __restrict__ dst0,
        float* __restrict__ logits, int H, int co_shift, int hc) {
    __shared__ float sea[128][EDIM];
    __shared__ int ssrc[128], sdst[128];
    int tid = threadIdx.x;
    int lane = tid & 63, wave = tid >> 6;
    int cbase = blockIdx.y * 256;
    int head = cbase >> co_shift;           // chunk lies inside one head (co % 256 == 0)
    int j = cbase + lane * 4;
    int e0 = blockIdx.x * 128;

    // stage ea (128 x 16 floats) as float4
    for (int t = tid; t < 128 * 4; t += 256) {
        int le = t >> 2, q = t & 3;
        int e = e0 + le;
        float4 v = make_float4(0.f, 0.f, 0.f, 0.f);
        if (e < ETOT) {
            const float* ea = (e < N_EDGES) ? edge_attr + (size_t)e * EDIM
                                            : ea_loop + (size_t)(e - N_EDGES) * EDIM;
            v = *(const float4*)(ea + q * 4);
        }
        *(float4*)&sea[le][q * 4] = v;
    }
    for (int t = tid; t < 128; t += 256) {
        int e = e0 + t;
        int s = 0, d = 0;
        if (e < ETOT) {
            if (e < N_EDGES) { s = src0[e]; d = dst0[e]; }
            else             { s = d = e - N_EDGES; }
        }
        ssrc[t] = s; sdst[t] = d;
    }
    __syncthreads();

    // We chunk in registers: 16 rows x 4 channels per lane
    float4 w[EDIM];
#pragma unroll
    for (int k = 0; k < EDIM; k++)
        w[k] = *(const float4*)(We + (size_t)k * hc + j);
    float4 a4 = *(const float4*)(att + j);

    int lbase = wave * 32;
#pragma unroll 2
    for (int i = 0; i < 32; i++) {
        int le = lbase + i;
        int e = e0 + le;
        if (e >= ETOT) break;               // wave-uniform
        int s = ssrc[le], d = sdst[le];
        float4 xlv = *(const float4*)(xl + (size_t)s * hc + j);
        float4 xrv = *(const float4*)(xr + (size_t)d * hc + j);
        float4 ee = make_float4(0.f, 0.f, 0.f, 0.f);
#pragma unroll
        for (int k = 0; k < EDIM; k++) {
            float c = sea[le][k];
            ee.x += c * w[k].x; ee.y += c * w[k].y;
            ee.z += c * w[k].z; ee.w += c * w[k].w;
        }
        float mx = xlv.x + xrv.x + ee.x;
        float my = xlv.y + xrv.y + ee.y;
        float mz = xlv.z + xrv.z + ee.z;
        float mw = xlv.w + xrv.w + ee.w;
        mx = (mx > 0.f) ? mx : 0.2f * mx;
        my = (my > 0.f) ? my : 0.2f * my;
        mz = (mz > 0.f) ? mz : 0.2f * mz;
        mw = (mw > 0.f) ? mw : 0.2f * mw;
        float p = mx * a4.x + my * a4.y + mz * a4.z + mw * a4.w;
#pragma unroll
        for (int off = 32; off > 0; off >>= 1)
            p += __shfl_down(p, off, 64);
        if (lane == 0)
            atomicAdd(&logits[(size_t)e * H + head], p);
    }
}

// ---------------- segmented softmax over incoming edges, in-place ----------------

__global__ void seg_softmax(const int* __restrict__ rowptr, const int* __restrict__ eid,
                            float* __restrict__ logits, int H) {
    int tid = blockIdx.x * 256 + threadIdx.x;
    if (tid >= N_NODES * H) return;
    int n = tid / H, h = tid - n * H;
    int b = rowptr[n], t = rowptr[n + 1];
    float mx = -1e30f;
    for (int i = b; i < t; i++) {
        float v = logits[(size_t)eid[i] * H + h];
        mx = fmaxf(mx, v);
    }
    float ssum = 0.f;
    for (int i = b; i < t; i++)
        ssum += expf(logits[(size_t)eid[i] * H + h] - mx);
    float inv = 1.f / ssum;
    for (int i = b; i < t; i++) {
        size_t idx = (size_t)eid[i] * H + h;
        logits[idx] = expf(logits[idx] - mx) * inv;
    }
}

// ---------------- aggregation v2 (float4, LDS-staged alpha/src) ----------------
// block per dst node; out[n,j] = relu(sum_e alpha[e,h]*xl[src_e,j] + bias[j])

__global__ __launch_bounds__(256) void aggregate2(
        const int* __restrict__ rowptr, const int* __restrict__ eid,
        const int* __restrict__ src0, const float* __restrict__ alpha,
        const float* __restrict__ xl, const float* __restrict__ bias,
        float* __restrict__ out, int H, int co_shift, int hc) {
    __shared__ int ssrc[64];
    __shared__ float salp[64][4];
    int n = blockIdx.x;
    int b = rowptr[n], t = rowptr[n + 1];
    int j0 = threadIdx.x * 4;
    int j1 = j0 + 1024;
    int h0 = j0 >> co_shift;
    int h1 = j1 >> co_shift;
    float4 acc0 = make_float4(0.f, 0.f, 0.f, 0.f);
    float4 acc1 = make_float4(0.f, 0.f, 0.f, 0.f);
    bool act0 = j0 < hc, act1 = j1 < hc;

    for (int cb = b; cb < t; cb += 64) {
        int m = min(64, t - cb);
        __syncthreads();
        for (int i = threadIdx.x; i < m; i += 256) {
            int e = eid[cb + i];
            int s = (e < N_EDGES) ? src0[e] : (e - N_EDGES);
            ssrc[i] = s;
            for (int h = 0; h < H; h++)
                salp[i][h] = alpha[(size_t)e * H + h];
        }
        __syncthreads();
        for (int i = 0; i < m; i++) {
            int s = ssrc[i];
            const float* base = xl + (size_t)s * hc;
            if (act0) {
                float a = salp[i][h0];
                float4 v = *(const float4*)(base + j0);
                acc0.x += a * v.x; acc0.y += a * v.y;
                acc0.z += a * v.z; acc0.w += a * v.w;
            }
            if (act1) {
                float a = salp[i][h1];
                float4 v = *(const float4*)(base + j1);
                acc1.x += a * v.x; acc1.y += a * v.y;
                acc1.z += a * v.z; acc1.w += a * v.w;
            }
        }
    }
    if (act0) {
        float4 bz = *(const float4*)(bias + j0);
        float4 o;
        o.x = fmaxf(acc0.x + bz.x, 0.f); o.y = fmaxf(acc0.y + bz.y, 0.f);
        o.z = fmaxf(acc0.z + bz.z, 0.f); o.w = fmaxf(acc0.w + bz.w, 0.f);
        *(float4*)(out + (size_t)n * hc + j0) = o;
    }
    if (act1) {
        float4 bz = *(const float4*)(bias + j1);
        float4 o;
        o.x = fmaxf(acc1.x + bz.x, 0.f); o.y = fmaxf(acc1.y + bz.y, 0.f);
        o.z = fmaxf(acc1.z + bz.z, 0.f); o.w = fmaxf(acc1.w + bz.w, 0.f);
        *(float4*)(out + (size_t)n * hc + j1) = o;
    }
}

// ---------------- pooling + MLP head ----------------

__global__ void pool_cnt(const int* __restrict__ batch, int* __restrict__ gcnt) {
    int n = blockIdx.x * 256 + threadIdx.x;
    if (n < N_NODES) atomicAdd(&gcnt[batch[n]], 1);
}

__global__ void pool_sum(const int* __restrict__ batch, const float* __restrict__ h,
                         float* __restrict__ pooled) {
    int tid = blockIdx.x * 256 + threadIdx.x;
    if (tid >= N_NODES * 256) return;
    int n = tid >> 8, c = tid & 255;
    atomicAdd(&pooled[batch[n] * 256 + c], h[tid]);
}

__global__ void mlp_head(const float* __restrict__ pooled, const int* __restrict__ gcnt,
                         const float* __restrict__ fc1w, const float* __restrict__ fc1b,
                         const float* __restrict__ fc2w, const float* __restrict__ fc2b,
                         float* __restrict__ out) {
    int g = threadIdx.x;
    if (g >= NGRAPHS) return;
    float inv = 1.f / (float)(gcnt[g] > 0 ? gcnt[g] : 1);
    float s[64];
#pragma unroll
    for (int j = 0; j < 64; j++) s[j] = fc1b[j];
    for (int c = 0; c < 256; c++) {
        float mv = pooled[g * 256 + c] * inv;
#pragma unroll
        for (int j = 0; j < 64; j++) s[j] += mv * fc1w[c * 64 + j];
    }
    float o = 0.f;
#pragma unroll
    for (int j = 0; j < 64; j++) o += fmaxf(s[j], 0.f) * fc2w[j];
    out[g] = o + fc2b[0];
}

// ---------------- launch ----------------

extern "C" void kernel_launch(void* const* d_in, const int* in_sizes, int n_in,
                              void* d_out, int out_size, void* d_ws, size_t ws_size,
                              hipStream_t stream) {
    const float* x         = (const float*)d_in[0];
    const int*   edge_index= (const int*)d_in[1];
    const float* edge_attr = (const float*)d_in[2];
    const int*   batch     = (const int*)d_in[3];
    const int* src0 = edge_index;
    const int* dst0 = edge_index + N_EDGES;

    const float *Wl[4], *bl[4], *Wr[4], *br[4], *We[4], *att[4], *bias[4];
    for (int i = 0; i < 4; i++) {
        int base = 4 + 7 * i;
        Wl[i]   = (const float*)d_in[base + 0];
        bl[i]   = (const float*)d_in[base + 1];
        Wr[i]   = (const float*)d_in[base + 2];
        br[i]   = (const float*)d_in[base + 3];
        We[i]   = (const float*)d_in[base + 4];
        att[i]  = (const float*)d_in[base + 5];
        bias[i] = (const float*)d_in[base + 6];
    }
    const float* fc1w = (const float*)d_in[32];
    const float* fc1b = (const float*)d_in[33];
    const float* fc2w = (const float*)d_in[34];
    const float* fc2b = (const float*)d_in[35];
    float* out = (float*)d_out;

    float* ws = (float*)d_ws;
    int*   rowptr  = (int*)(ws + 0);            // 8001 ints
    int*   woff    = (int*)(ws + 8064);         // 8000 ints
    int*   eid     = (int*)(ws + 16128);        // 72000 ints
    float* ea_loop = ws + 88128;                // 8000*16
    float* logits  = ws + 216128;               // 72000*3
    float* xl      = ws + 432128;               // 8000*1536
    float* xr      = xl  + 12288000;
    float* hb0     = xr  + 12288000;
    float* hb1     = hb0 + 12288000;
    float* pooled  = hb1 + 12288000;            // 64*256
    int*   gcnt    = (int*)(pooled + 16384);    // 64

    hipMemsetAsync(woff, 0, N_NODES * sizeof(int), stream);
    count_deg<<<(N_EDGES + 255) / 256, 256, 0, stream>>>(dst0, woff);
    scan_deg<<<1, 256, 0, stream>>>(woff, rowptr);
    copy_off<<<(N_NODES + 255) / 256, 256, 0, stream>>>(rowptr, woff);
    fill_eid<<<(ETOT + 255) / 256, 256, 0, stream>>>(dst0, woff, eid);
    ea_loop_kernel<<<(N_NODES + 255) / 256, 256, 0, stream>>>(rowptr, eid, edge_attr, ea_loop);

    const int IN[4] = {256, 1536, 1024, 512};
    const int HH[4] = {3, 2, 2, 1};
    const int CO[4] = {512, 512, 256, 256};
    const int CS[4] = {9, 9, 8, 8};            // log2(co)
    const float* hin = x;
    float* houts[4] = {hb0, hb1, hb0, hb1};

    for (int L = 0; L < 4; L++) {
        int K = IN[L], H = HH[L], co = CO[L], hc = H * co, cs = CS[L];
        (void)co;
        dim3 gg(hc / 128, (N_NODES + 127) / 128);
        gemm_bias<<<gg, 256, 0, stream>>>(hin, Wl[L], bl[L], xl, N_NODES, K, hc);
        gemm_bias<<<gg, 256, 0, stream>>>(hin, Wr[L], br[L], xr, N_NODES, K, hc);
        hipMemsetAsync(logits, 0, (size_t)ETOT * H * sizeof(float), stream);
        dim3 gl((ETOT + 127) / 128, hc / 256);
        edge_logits2<<<gl, 256, 0, stream>>>(
            xl, xr, We[L], att[L], edge_attr, ea_loop, src0, dst0, logits, H, cs, hc);
        seg_softmax<<<(N_NODES * H + 255) / 256, 256, 0, stream>>>(rowptr, eid, logits, H);
        aggregate2<<<N_NODES, 256, 0, stream>>>(
            rowptr, eid, src0, logits, xl, bias[L], houts[L], H, cs, hc);
        hin = houts[L];
    }

    hipMemsetAsync(pooled, 0, (16384 + 64) * sizeof(float), stream);
    pool_cnt<<<(N_NODES + 255) / 256, 256, 0, stream>>>(batch, gcnt);
    pool_sum<<<(N_NODES * 256 + 255) / 256, 256, 0, stream>>>(batch, hin, pooled);
    mlp_head<<<1, 64, 0, stream>>>(pooled, gcnt, fc1w, fc1b, fc2w, fc2b, out);
}

// Round 4
// 1563.061 us; speedup vs baseline: 1.7498x; 1.4021x over previous
//
#include <hip/hip_runtime.h>
#include <math.h>

#define N_NODES 8000
#define N_EDGES 64000
#define ETOT    (N_EDGES + N_NODES)   // 72000, self-loops appended
#define EDIM    16
#define NGRAPHS 64

typedef __attribute__((ext_vector_type(8))) short short8v;
typedef __attribute__((ext_vector_type(4))) short short4v;
typedef __attribute__((ext_vector_type(4))) float f32x4;

__device__ inline unsigned short f2bf(float f) {
    unsigned u = __builtin_bit_cast(unsigned, f);
    unsigned r = (u + 0x7FFF + ((u >> 16) & 1)) >> 16;   // RNE
    return (unsigned short)r;
}
__device__ inline float bf2f(unsigned short b) {
    unsigned u = ((unsigned)b) << 16;
    return __builtin_bit_cast(float, u);
}

// ---------------- CSR build ----------------

__global__ void count_deg(const int* __restrict__ dst0, int* __restrict__ deg) {
    int e = blockIdx.x * 256 + threadIdx.x;
    if (e < N_EDGES) atomicAdd(&deg[dst0[e]], 1);
}

__global__ void scan_deg(const int* __restrict__ deg, int* __restrict__ rowptr) {
    __shared__ int sh[256];
    __shared__ int carry_s;
    int t = threadIdx.x;
    if (t == 0) { carry_s = 0; rowptr[0] = 0; }
    __syncthreads();
    for (int base = 0; base < N_NODES; base += 256) {
        int i = base + t;
        int v = (i < N_NODES) ? (deg[i] + 1) : 0;   // +1 self loop
        sh[t] = v;
        __syncthreads();
        for (int off = 1; off < 256; off <<= 1) {
            int u = (t >= off) ? sh[t - off] : 0;
            __syncthreads();
            sh[t] += u;
            __syncthreads();
        }
        int incl = sh[t] + carry_s;
        if (i < N_NODES) rowptr[i + 1] = incl;
        __syncthreads();
        if (t == 255) carry_s = incl;
        __syncthreads();
    }
}

__global__ void copy_off(const int* __restrict__ rowptr, int* __restrict__ woff) {
    int i = blockIdx.x * 256 + threadIdx.x;
    if (i < N_NODES) woff[i] = rowptr[i];
}

__global__ void fill_eid(const int* __restrict__ dst0, int* __restrict__ woff,
                         int* __restrict__ eid) {
    int i = blockIdx.x * 256 + threadIdx.x;
    if (i < N_EDGES) {
        int pos = atomicAdd(&woff[dst0[i]], 1);
        eid[pos] = i;
    } else if (i < ETOT) {
        int n = i - N_EDGES;
        int pos = atomicAdd(&woff[n], 1);
        eid[pos] = i;
    }
}

__global__ void ea_loop_kernel(const int* __restrict__ rowptr, const int* __restrict__ eid,
                               const float* __restrict__ edge_attr, float* __restrict__ ea_loop) {
    int n = blockIdx.x * 256 + threadIdx.x;
    if (n >= N_NODES) return;
    float s[EDIM];
#pragma unroll
    for (int k = 0; k < EDIM; k++) s[k] = 0.f;
    int cnt = 0;
    int b = rowptr[n], t = rowptr[n + 1];
    for (int i = b; i < t; i++) {
        int e = eid[i];
        if (e < N_EDGES) {
            cnt++;
            const float* ea = edge_attr + (size_t)e * EDIM;
#pragma unroll
            for (int k = 0; k < EDIM; k++) s[k] += ea[k];
        }
    }
    float inv = 1.f / (float)(cnt > 0 ? cnt : 1);
#pragma unroll
    for (int k = 0; k < EDIM; k++) ea_loop[(size_t)n * EDIM + k] = s[k] * inv;
}

// ---------------- weight transpose + bf16 split: W[K][N] -> WT_hi/lo[N][K] ----------------

__global__ __launch_bounds__(256) void cvt_wt_t(
        const float* __restrict__ W, short* __restrict__ WTh, short* __restrict__ WTl,
        int K, int Nc) {
    __shared__ float sh[32][33];
    int t = threadIdx.x;
    int tx = t & 31, ty = t >> 5;            // 32 x 8
    int n0 = blockIdx.x * 32, k0 = blockIdx.y * 32;
#pragma unroll
    for (int j = 0; j < 4; j++)
        sh[ty + j * 8][tx] = W[(size_t)(k0 + ty + j * 8) * Nc + n0 + tx];
    __syncthreads();
#pragma unroll
    for (int j = 0; j < 4; j++) {
        int row = ty + j * 8;                 // local n
        float v = sh[tx][row];
        unsigned short h = f2bf(v);
        unsigned short l = f2bf(v - bf2f(h));
        size_t idx = (size_t)(n0 + row) * K + k0 + tx;
        WTh[idx] = (short)h;
        WTl[idx] = (short)l;
    }
}

// ---------------- bf16x3 MFMA GEMM: C[M,Nc] = A[M,K] @ BT^T + bias ----------------
// A fp32 row-major (split hi/lo on the fly); BT_hi/lo bf16 [Nc][K].
// Block 256 = 4 waves (2x2), wave tile 64x64 via 4x4 of 16x16x32 MFMA.

#define LDK 40   // padded LDS row stride in shorts (32 + 8)

__global__ __launch_bounds__(256) void gemm_mfma(
        const float* __restrict__ A, const short* __restrict__ BTh,
        const short* __restrict__ BTl, const float* __restrict__ bias,
        float* __restrict__ C, int M, int K, int Nc) {
    __shared__ short Ah[128 * LDK];
    __shared__ short Al[128 * LDK];
    __shared__ short Bh[128 * LDK];
    __shared__ short Bl[128 * LDK];
    int t = threadIdx.x;
    int m0 = blockIdx.y * 128, n0 = blockIdx.x * 128;
    int lane = t & 63, wave = t >> 6;
    int wm = (wave >> 1) * 64, wn = (wave & 1) * 64;
    int fr = lane & 15, koff = (lane >> 4) * 8;

    f32x4 acc[4][4];
#pragma unroll
    for (int i = 0; i < 4; i++)
#pragma unroll
        for (int j = 0; j < 4; j++) acc[i][j] = (f32x4)(0.f);

    int brow = t >> 1, bseg = t & 1;          // B: 16-short (32B) chunk per thread

    for (int k0 = 0; k0 < K; k0 += 32) {
        __syncthreads();
        // stage A with on-the-fly hi/lo split: 128 rows x 32 fp32
#pragma unroll
        for (int i = 0; i < 4; i++) {
            int f = t + i * 256;
            int row = f >> 3, seg = f & 7;
            float4 v = make_float4(0.f, 0.f, 0.f, 0.f);
            if (m0 + row < M)
                v = *(const float4*)(A + (size_t)(m0 + row) * K + k0 + seg * 4);
            unsigned short h0 = f2bf(v.x), h1 = f2bf(v.y), h2 = f2bf(v.z), h3 = f2bf(v.w);
            short4v hv = { (short)h0, (short)h1, (short)h2, (short)h3 };
            short4v lv = { (short)f2bf(v.x - bf2f(h0)), (short)f2bf(v.y - bf2f(h1)),
                           (short)f2bf(v.z - bf2f(h2)), (short)f2bf(v.w - bf2f(h3)) };
            *(short4v*)&Ah[row * LDK + seg * 4] = hv;
            *(short4v*)&Al[row * LDK + seg * 4] = lv;
        }
        // stage B tiles: 128 rows x 32 shorts; each thread does a full 16-short chunk
        {
            const short* gh = BTh + (size_t)(n0 + brow) * K + k0 + bseg * 16;
            const short* gl = BTl + (size_t)(n0 + brow) * K + k0 + bseg * 16;
            int lo = brow * LDK + bseg * 16;
            *(short8v*)&Bh[lo]     = *(const short8v*)gh;
            *(short8v*)&Bh[lo + 8] = *(const short8v*)(gh + 8);
            *(short8v*)&Bl[lo]     = *(const short8v*)gl;
            *(short8v*)&Bl[lo + 8] = *(const short8v*)(gl + 8);
        }
        __syncthreads();

        short8v ah[4], al[4], bh[4], bl[4];
#pragma unroll
        for (int mi = 0; mi < 4; mi++) {
            int r = (wm + mi * 16 + fr) * LDK + koff;
            ah[mi] = *(short8v*)&Ah[r];
            al[mi] = *(short8v*)&Al[r];
        }
#pragma unroll
        for (int ni = 0; ni < 4; ni++) {
            int r = (wn + ni * 16 + fr) * LDK + koff;
            bh[ni] = *(short8v*)&Bh[r];
            bl[ni] = *(short8v*)&Bl[r];
        }
#pragma unroll
        for (int mi = 0; mi < 4; mi++)
#pragma unroll
            for (int ni = 0; ni < 4; ni++) {
                acc[mi][ni] = __builtin_amdgcn_mfma_f32_16x16x32_bf16(
                    al[mi], bh[ni], acc[mi][ni], 0, 0, 0);
                acc[mi][ni] = __builtin_amdgcn_mfma_f32_16x16x32_bf16(
                    ah[mi], bl[ni], acc[mi][ni], 0, 0, 0);
                acc[mi][ni] = __builtin_amdgcn_mfma_f32_16x16x32_bf16(
                    ah[mi], bh[ni], acc[mi][ni], 0, 0, 0);
            }
    }

    // epilogue: C/D layout col = lane&15, row = (lane>>4)*4 + reg
    int rbase = (lane >> 4) * 4;
#pragma unroll
    for (int ni = 0; ni < 4; ni++) {
        int col = n0 + wn + ni * 16 + fr;
        float bz = bias[col];
#pragma unroll
        for (int mi = 0; mi < 4; mi++) {
            int row0 = m0 + wm + mi * 16 + rbase;
#pragma unroll
            for (int r = 0; r < 4; r++) {
                int row = row0 + r;
                if (row < M) C[(size_t)row * Nc + col] = acc[mi][ni][r] + bz;
            }
        }
    }
}

// ---------------- edge logits v2 ----------------

__global__ __launch_bounds__(256) void edge_logits2(
        const float* __restrict__ xl, const float* __restrict__ xr,
        const float* __restrict__ We, const float* __restrict__ att,
        const float* __restrict__ edge_attr, const float* __restrict__ ea_loop,
        const int* __restrict__ src0, const int* __restrict__ dst0,
        float* __restrict__ logits, int H, int co_shift, int hc) {
    __shared__ float sea[128][EDIM];
    __shared__ int ssrc[128], sdst[128];
    int tid = threadIdx.x;
    int lane = tid & 63, wave = tid >> 6;
    int cbase = blockIdx.y * 256;
    int head = cbase >> co_shift;
    int j = cbase + lane * 4;
    int e0 = blockIdx.x * 128;

    for (int t = tid; t < 128 * 4; t += 256) {
        int le = t >> 2, q = t & 3;
        int e = e0 + le;
        float4 v = make_float4(0.f, 0.f, 0.f, 0.f);
        if (e < ETOT) {
            const float* ea = (e < N_EDGES) ? edge_attr + (size_t)e * EDIM
                                            : ea_loop + (size_t)(e - N_EDGES) * EDIM;
            v = *(const float4*)(ea + q * 4);
        }
        *(float4*)&sea[le][q * 4] = v;
    }
    for (int t = tid; t < 128; t += 256) {
        int e = e0 + t;
        int s = 0, d = 0;
        if (e < ETOT) {
            if (e < N_EDGES) { s = src0[e]; d = dst0[e]; }
            else             { s = d = e - N_EDGES; }
        }
        ssrc[t] = s; sdst[t] = d;
    }
    __syncthreads();

    float4 w[EDIM];
#pragma unroll
    for (int k = 0; k < EDIM; k++)
        w[k] = *(const float4*)(We + (size_t)k * hc + j);
    float4 a4 = *(const float4*)(att + j);

    int lbase = wave * 32;
#pragma unroll 2
    for (int i = 0; i < 32; i++) {
        int le = lbase + i;
        int e = e0 + le;
        if (e >= ETOT) break;
        int s = ssrc[le], d = sdst[le];
        float4 xlv = *(const float4*)(xl + (size_t)s * hc + j);
        float4 xrv = *(const float4*)(xr + (size_t)d * hc + j);
        float4 ee = make_float4(0.f, 0.f, 0.f, 0.f);
#pragma unroll
        for (int k = 0; k < EDIM; k++) {
            float c = sea[le][k];
            ee.x += c * w[k].x; ee.y += c * w[k].y;
            ee.z += c * w[k].z; ee.w += c * w[k].w;
        }
        float mx = xlv.x + xrv.x + ee.x;
        float my = xlv.y + xrv.y + ee.y;
        float mz = xlv.z + xrv.z + ee.z;
        float mw = xlv.w + xrv.w + ee.w;
        mx = (mx > 0.f) ? mx : 0.2f * mx;
        my = (my > 0.f) ? my : 0.2f * my;
        mz = (mz > 0.f) ? mz : 0.2f * mz;
        mw = (mw > 0.f) ? mw : 0.2f * mw;
        float p = mx * a4.x + my * a4.y + mz * a4.z + mw * a4.w;
#pragma unroll
        for (int off = 32; off > 0; off >>= 1)
            p += __shfl_down(p, off, 64);
        if (lane == 0)
            atomicAdd(&logits[(size_t)e * H + head], p);
    }
}

// ---------------- segmented softmax ----------------

__global__ void seg_softmax(const int* __restrict__ rowptr, const int* __restrict__ eid,
                            float* __restrict__ logits, int H) {
    int tid = blockIdx.x * 256 + threadIdx.x;
    if (tid >= N_NODES * H) return;
    int n = tid / H, h = tid - n * H;
    int b = rowptr[n], t = rowptr[n + 1];
    float mx = -1e30f;
    for (int i = b; i < t; i++) {
        float v = logits[(size_t)eid[i] * H + h];
        mx = fmaxf(mx, v);
    }
    float ssum = 0.f;
    for (int i = b; i < t; i++)
        ssum += expf(logits[(size_t)eid[i] * H + h] - mx);
    float inv = 1.f / ssum;
    for (int i = b; i < t; i++) {
        size_t idx = (size_t)eid[i] * H + h;
        logits[idx] = expf(logits[idx] - mx) * inv;
    }
}

// ---------------- aggregation v2 ----------------

__global__ __launch_bounds__(256) void aggregate2(
        const int* __restrict__ rowptr, const int* __restrict__ eid,
        const int* __restrict__ src0, const float* __restrict__ alpha,
        const float* __restrict__ xl, const float* __restrict__ bias,
        float* __restrict__ out, int H, int co_shift, int hc) {
    __shared__ int ssrc[64];
    __shared__ float salp[64][4];
    int n = blockIdx.x;
    int b = rowptr[n], t = rowptr[n + 1];
    int j0 = threadIdx.x * 4;
    int j1 = j0 + 1024;
    int h0 = j0 >> co_shift;
    int h1 = j1 >> co_shift;
    float4 acc0 = make_float4(0.f, 0.f, 0.f, 0.f);
    float4 acc1 = make_float4(0.f, 0.f, 0.f, 0.f);
    bool act0 = j0 < hc, act1 = j1 < hc;

    for (int cb = b; cb < t; cb += 64) {
        int m = min(64, t - cb);
        __syncthreads();
        for (int i = threadIdx.x; i < m; i += 256) {
            int e = eid[cb + i];
            int s = (e < N_EDGES) ? src0[e] : (e - N_EDGES);
            ssrc[i] = s;
            for (int h = 0; h < H; h++)
                salp[i][h] = alpha[(size_t)e * H + h];
        }
        __syncthreads();
        for (int i = 0; i < m; i++) {
            int s = ssrc[i];
            const float* base = xl + (size_t)s * hc;
            if (act0) {
                float a = salp[i][h0];
                float4 v = *(const float4*)(base + j0);
                acc0.x += a * v.x; acc0.y += a * v.y;
                acc0.z += a * v.z; acc0.w += a * v.w;
            }
            if (act1) {
                float a = salp[i][h1];
                float4 v = *(const float4*)(base + j1);
                acc1.x += a * v.x; acc1.y += a * v.y;
                acc1.z += a * v.z; acc1.w += a * v.w;
            }
        }
    }
    if (act0) {
        float4 bz = *(const float4*)(bias + j0);
        float4 o;
        o.x = fmaxf(acc0.x + bz.x, 0.f); o.y = fmaxf(acc0.y + bz.y, 0.f);
        o.z = fmaxf(acc0.z + bz.z, 0.f); o.w = fmaxf(acc0.w + bz.w, 0.f);
        *(float4*)(out + (size_t)n * hc + j0) = o;
    }
    if (act1) {
        float4 bz = *(const float4*)(bias + j1);
        float4 o;
        o.x = fmaxf(acc1.x + bz.x, 0.f); o.y = fmaxf(acc1.y + bz.y, 0.f);
        o.z = fmaxf(acc1.z + bz.z, 0.f); o.w = fmaxf(acc1.w + bz.w, 0.f);
        *(float4*)(out + (size_t)n * hc + j1) = o;
    }
}

// ---------------- pooling + MLP head ----------------

__global__ void pool_cnt(const int* __restrict__ batch, int* __restrict__ gcnt) {
    int n = blockIdx.x * 256 + threadIdx.x;
    if (n < N_NODES) atomicAdd(&gcnt[batch[n]], 1);
}

__global__ void pool_sum(const int* __restrict__ batch, const float* __restrict__ h,
                         float* __restrict__ pooled) {
    int tid = blockIdx.x * 256 + threadIdx.x;
    if (tid >= N_NODES * 256) return;
    int n = tid >> 8, c = tid & 255;
    atomicAdd(&pooled[batch[n] * 256 + c], h[tid]);
}

__global__ void mlp_head(const float* __restrict__ pooled, const int* __restrict__ gcnt,
                         const float* __restrict__ fc1w, const float* __restrict__ fc1b,
                         const float* __restrict__ fc2w, const float* __restrict__ fc2b,
                         float* __restrict__ out) {
    int g = threadIdx.x;
    if (g >= NGRAPHS) return;
    float inv = 1.f / (float)(gcnt[g] > 0 ? gcnt[g] : 1);
    float s[64];
#pragma unroll
    for (int j = 0; j < 64; j++) s[j] = fc1b[j];
    for (int c = 0; c < 256; c++) {
        float mv = pooled[g * 256 + c] * inv;
#pragma unroll
        for (int j = 0; j < 64; j++) s[j] += mv * fc1w[c * 64 + j];
    }
    float o = 0.f;
#pragma unroll
    for (int j = 0; j < 64; j++) o += fmaxf(s[j], 0.f) * fc2w[j];
    out[g] = o + fc2b[0];
}

// ---------------- launch ----------------

extern "C" void kernel_launch(void* const* d_in, const int* in_sizes, int n_in,
                              void* d_out, int out_size, void* d_ws, size_t ws_size,
                              hipStream_t stream) {
    const float* x         = (const float*)d_in[0];
    const int*   edge_index= (const int*)d_in[1];
    const float* edge_attr = (const float*)d_in[2];
    const int*   batch     = (const int*)d_in[3];
    const int* src0 = edge_index;
    const int* dst0 = edge_index + N_EDGES;

    const float *Wl[4], *bl[4], *Wr[4], *br[4], *We[4], *att[4], *bias[4];
    for (int i = 0; i < 4; i++) {
        int base = 4 + 7 * i;
        Wl[i]   = (const float*)d_in[base + 0];
        bl[i]   = (const float*)d_in[base + 1];
        Wr[i]   = (const float*)d_in[base + 2];
        br[i]   = (const float*)d_in[base + 3];
        We[i]   = (const float*)d_in[base + 4];
        att[i]  = (const float*)d_in[base + 5];
        bias[i] = (const float*)d_in[base + 6];
    }
    const float* fc1w = (const float*)d_in[32];
    const float* fc1b = (const float*)d_in[33];
    const float* fc2w = (const float*)d_in[34];
    const float* fc2b = (const float*)d_in[35];
    float* out = (float*)d_out;

    float* ws = (float*)d_ws;
    int*   rowptr  = (int*)(ws + 0);            // 8001 ints
    int*   woff    = (int*)(ws + 8064);         // 8000 ints
    int*   eid     = (int*)(ws + 16128);        // 72000 ints
    float* ea_loop = ws + 88128;                // 8000*16
    float* logits  = ws + 216128;               // 72000*3
    float* xl      = ws + 432128;               // 8000*1536
    float* xr      = xl  + 12288000;
    float* hb0     = xr  + 12288000;
    float* hb1     = hb0 + 12288000;
    float* pooled  = hb1 + 12288000;            // 64*256
    int*   gcnt    = (int*)(pooled + 16384);    // 64
    short* wth     = (short*)(ws + 49600576);   // 1536*1536 shorts
    short* wtl     = (short*)(ws + 50780224);   // 1536*1536 shorts

    hipMemsetAsync(woff, 0, N_NODES * sizeof(int), stream);
    count_deg<<<(N_EDGES + 255) / 256, 256, 0, stream>>>(dst0, woff);
    scan_deg<<<1, 256, 0, stream>>>(woff, rowptr);
    copy_off<<<(N_NODES + 255) / 256, 256, 0, stream>>>(rowptr, woff);
    fill_eid<<<(ETOT + 255) / 256, 256, 0, stream>>>(dst0, woff, eid);
    ea_loop_kernel<<<(N_NODES + 255) / 256, 256, 0, stream>>>(rowptr, eid, edge_attr, ea_loop);

    const int IN[4] = {256, 1536, 1024, 512};
    const int HH[4] = {3, 2, 2, 1};
    const int CO[4] = {512, 512, 256, 256};
    const int CS[4] = {9, 9, 8, 8};            // log2(co)
    const float* hin = x;
    float* houts[4] = {hb0, hb1, hb0, hb1};

    for (int L = 0; L < 4; L++) {
        int K = IN[L], H = HH[L], co = CO[L], hc = H * co, cs = CS[L];
        (void)co;
        dim3 gg(hc / 128, (N_NODES + 127) / 128);
        dim3 gw(hc / 32, K / 32);
        cvt_wt_t<<<gw, 256, 0, stream>>>(Wl[L], wth, wtl, K, hc);
        gemm_mfma<<<gg, 256, 0, stream>>>(hin, wth, wtl, bl[L], xl, N_NODES, K, hc);
        cvt_wt_t<<<gw, 256, 0, stream>>>(Wr[L], wth, wtl, K, hc);
        gemm_mfma<<<gg, 256, 0, stream>>>(hin, wth, wtl, br[L], xr, N_NODES, K, hc);
        hipMemsetAsync(logits, 0, (size_t)ETOT * H * sizeof(float), stream);
        dim3 gl((ETOT + 127) / 128, hc / 256);
        edge_logits2<<<gl, 256, 0, stream>>>(
            xl, xr, We[L], att[L], edge_attr, ea_loop, src0, dst0, logits, H, cs, hc);
        seg_softmax<<<(N_NODES * H + 255) / 256, 256, 0, stream>>>(rowptr, eid, logits, H);
        aggregate2<<<N_NODES, 256, 0, stream>>>(
            rowptr, eid, src0, logits, xl, bias[L], houts[L], H, cs, hc);
        hin = houts[L];
    }

    hipMemsetAsync(pooled, 0, (16384 + 64) * sizeof(float), stream);
    pool_cnt<<<(N_NODES + 255) / 256, 256, 0, stream>>>(batch, gcnt);
    pool_sum<<<(N_NODES * 256 + 255) / 256, 256, 0, stream>>>(batch, hin, pooled);
    mlp_head<<<1, 64, 0, stream>>>(pooled, gcnt, fc1w, fc1b, fc2w, fc2b, out);
}

// Round 6
// 1562.829 us; speedup vs baseline: 1.7500x; 1.0001x over previous
//
#include <hip/hip_runtime.h>
#include <math.h>

#define N_NODES 8000
#define N_EDGES 64000
#define ETOT    (N_EDGES + N_NODES)   // 72000, self-loops appended
#define EDIM    16
#define NGRAPHS 64

typedef __attribute__((ext_vector_type(8))) short short8v;
typedef __attribute__((ext_vector_type(4))) short short4v;
typedef __attribute__((ext_vector_type(4))) float f32x4;

__device__ inline unsigned short f2bf(float f) {
    unsigned u = __builtin_bit_cast(unsigned, f);
    unsigned r = (u + 0x7FFF + ((u >> 16) & 1)) >> 16;   // RNE
    return (unsigned short)r;
}
__device__ inline float bf2f(unsigned short b) {
    unsigned u = ((unsigned)b) << 16;
    return __builtin_bit_cast(float, u);
}

// ---------------- CSR build ----------------

__global__ void count_deg(const int* __restrict__ dst0, int* __restrict__ deg) {
    int e = blockIdx.x * 256 + threadIdx.x;
    if (e < N_EDGES) atomicAdd(&deg[dst0[e]], 1);
}

__global__ void scan_deg(const int* __restrict__ deg, int* __restrict__ rowptr) {
    __shared__ int sh[256];
    __shared__ int carry_s;
    int t = threadIdx.x;
    if (t == 0) { carry_s = 0; rowptr[0] = 0; }
    __syncthreads();
    for (int base = 0; base < N_NODES; base += 256) {
        int i = base + t;
        int v = (i < N_NODES) ? (deg[i] + 1) : 0;   // +1 self loop
        sh[t] = v;
        __syncthreads();
        for (int off = 1; off < 256; off <<= 1) {
            int u = (t >= off) ? sh[t - off] : 0;
            __syncthreads();
            sh[t] += u;
            __syncthreads();
        }
        int incl = sh[t] + carry_s;
        if (i < N_NODES) rowptr[i + 1] = incl;
        __syncthreads();
        if (t == 255) carry_s = incl;
        __syncthreads();
    }
}

__global__ void copy_off(const int* __restrict__ rowptr, int* __restrict__ woff) {
    int i = blockIdx.x * 256 + threadIdx.x;
    if (i < N_NODES) woff[i] = rowptr[i];
}

__global__ void fill_eid(const int* __restrict__ dst0, int* __restrict__ woff,
                         int* __restrict__ eid) {
    int i = blockIdx.x * 256 + threadIdx.x;
    if (i < N_EDGES) {
        int pos = atomicAdd(&woff[dst0[i]], 1);
        eid[pos] = i;
    } else if (i < ETOT) {
        int n = i - N_EDGES;
        int pos = atomicAdd(&woff[n], 1);
        eid[pos] = i;
    }
}

// csr_dst[i] = owning node for CSR position i
__global__ void csr_fill_dst(const int* __restrict__ rowptr, int* __restrict__ csr_dst) {
    int n = blockIdx.x * 256 + threadIdx.x;
    if (n >= N_NODES) return;
    int b = rowptr[n], t = rowptr[n + 1];
    for (int i = b; i < t; i++) csr_dst[i] = n;
}

// per-dst mean of incoming edge_attr (fill_value='mean'); isolated node -> 0
__global__ void ea_loop_kernel(const int* __restrict__ rowptr, const int* __restrict__ eid,
                               const float* __restrict__ edge_attr, float* __restrict__ ea_loop) {
    int n = blockIdx.x * 256 + threadIdx.x;
    if (n >= N_NODES) return;
    float s[EDIM];
#pragma unroll
    for (int k = 0; k < EDIM; k++) s[k] = 0.f;
    int cnt = 0;
    int b = rowptr[n], t = rowptr[n + 1];
    for (int i = b; i < t; i++) {
        int e = eid[i];
        if (e < N_EDGES) {
            cnt++;
            const float* ea = edge_attr + (size_t)e * EDIM;
#pragma unroll
            for (int k = 0; k < EDIM; k++) s[k] += ea[k];
        }
    }
    float inv = 1.f / (float)(cnt > 0 ? cnt : 1);
#pragma unroll
    for (int k = 0; k < EDIM; k++) ea_loop[(size_t)n * EDIM + k] = s[k] * inv;
}

// csr_src[i] + contiguous edge_attr copy in CSR order
__global__ void csr_srcea(const int* __restrict__ eid, const int* __restrict__ src0,
                          const float* __restrict__ edge_attr, const float* __restrict__ ea_loop,
                          int* __restrict__ csr_src, float* __restrict__ ea_csr) {
    int t = blockIdx.x * 256 + threadIdx.x;
    int i = t >> 2, q = t & 3;
    if (i >= ETOT) return;
    int e = eid[i];
    int s = (e < N_EDGES) ? src0[e] : (e - N_EDGES);
    if (q == 0) csr_src[i] = s;
    const float* ea = (e < N_EDGES) ? edge_attr + (size_t)e * EDIM
                                    : ea_loop + (size_t)(e - N_EDGES) * EDIM;
    *(float4*)(ea_csr + (size_t)i * EDIM + q * 4) = *(const float4*)(ea + q * 4);
}

// ---------------- weight transpose + bf16 split: W[K][N] -> WT_hi/lo[N][K] ----------------

__global__ __launch_bounds__(256) void cvt_wt_t(
        const float* __restrict__ W, short* __restrict__ WTh, short* __restrict__ WTl,
        int K, int Nc) {
    __shared__ float sh[32][33];
    int t = threadIdx.x;
    int tx = t & 31, ty = t >> 5;            // 32 x 8
    int n0 = blockIdx.x * 32, k0 = blockIdx.y * 32;
#pragma unroll
    for (int j = 0; j < 4; j++)
        sh[ty + j * 8][tx] = W[(size_t)(k0 + ty + j * 8) * Nc + n0 + tx];
    __syncthreads();
#pragma unroll
    for (int j = 0; j < 4; j++) {
        int row = ty + j * 8;                 // local n
        float v = sh[tx][row];
        unsigned short h = f2bf(v);
        unsigned short l = f2bf(v - bf2f(h));
        size_t idx = (size_t)(n0 + row) * K + k0 + tx;
        WTh[idx] = (short)h;
        WTl[idx] = (short)l;
    }
}

// ---------------- bf16x3 MFMA GEMM ----------------

#define LDK 40   // padded LDS row stride in shorts (32 + 8)

__global__ __launch_bounds__(256) void gemm_mfma(
        const float* __restrict__ A, const short* __restrict__ BTh,
        const short* __restrict__ BTl, const float* __restrict__ bias,
        float* __restrict__ C, int M, int K, int Nc) {
    __shared__ short Ah[128 * LDK];
    __shared__ short Al[128 * LDK];
    __shared__ short Bh[128 * LDK];
    __shared__ short Bl[128 * LDK];
    int t = threadIdx.x;
    int m0 = blockIdx.y * 128, n0 = blockIdx.x * 128;
    int lane = t & 63, wave = t >> 6;
    int wm = (wave >> 1) * 64, wn = (wave & 1) * 64;
    int fr = lane & 15, koff = (lane >> 4) * 8;

    f32x4 acc[4][4];
#pragma unroll
    for (int i = 0; i < 4; i++)
#pragma unroll
        for (int j = 0; j < 4; j++) acc[i][j] = (f32x4)(0.f);

    int brow = t >> 1, bseg = t & 1;

    for (int k0 = 0; k0 < K; k0 += 32) {
        __syncthreads();
#pragma unroll
        for (int i = 0; i < 4; i++) {
            int f = t + i * 256;
            int row = f >> 3, seg = f & 7;
            float4 v = make_float4(0.f, 0.f, 0.f, 0.f);
            if (m0 + row < M)
                v = *(const float4*)(A + (size_t)(m0 + row) * K + k0 + seg * 4);
            unsigned short h0 = f2bf(v.x), h1 = f2bf(v.y), h2 = f2bf(v.z), h3 = f2bf(v.w);
            short4v hv = { (short)h0, (short)h1, (short)h2, (short)h3 };
            short4v lv = { (short)f2bf(v.x - bf2f(h0)), (short)f2bf(v.y - bf2f(h1)),
                           (short)f2bf(v.z - bf2f(h2)), (short)f2bf(v.w - bf2f(h3)) };
            *(short4v*)&Ah[row * LDK + seg * 4] = hv;
            *(short4v*)&Al[row * LDK + seg * 4] = lv;
        }
        {
            const short* gh = BTh + (size_t)(n0 + brow) * K + k0 + bseg * 16;
            const short* gl = BTl + (size_t)(n0 + brow) * K + k0 + bseg * 16;
            int lo = brow * LDK + bseg * 16;
            *(short8v*)&Bh[lo]     = *(const short8v*)gh;
            *(short8v*)&Bh[lo + 8] = *(const short8v*)(gh + 8);
            *(short8v*)&Bl[lo]     = *(const short8v*)gl;
            *(short8v*)&Bl[lo + 8] = *(const short8v*)(gl + 8);
        }
        __syncthreads();

        short8v ah[4], al[4], bh[4], bl[4];
#pragma unroll
        for (int mi = 0; mi < 4; mi++) {
            int r = (wm + mi * 16 + fr) * LDK + koff;
            ah[mi] = *(short8v*)&Ah[r];
            al[mi] = *(short8v*)&Al[r];
        }
#pragma unroll
        for (int ni = 0; ni < 4; ni++) {
            int r = (wn + ni * 16 + fr) * LDK + koff;
            bh[ni] = *(short8v*)&Bh[r];
            bl[ni] = *(short8v*)&Bl[r];
        }
#pragma unroll
        for (int mi = 0; mi < 4; mi++)
#pragma unroll
            for (int ni = 0; ni < 4; ni++) {
                acc[mi][ni] = __builtin_amdgcn_mfma_f32_16x16x32_bf16(
                    al[mi], bh[ni], acc[mi][ni], 0, 0, 0);
                acc[mi][ni] = __builtin_amdgcn_mfma_f32_16x16x32_bf16(
                    ah[mi], bl[ni], acc[mi][ni], 0, 0, 0);
                acc[mi][ni] = __builtin_amdgcn_mfma_f32_16x16x32_bf16(
                    ah[mi], bh[ni], acc[mi][ni], 0, 0, 0);
            }
    }

    int rbase = (lane >> 4) * 4;
#pragma unroll
    for (int ni = 0; ni < 4; ni++) {
        int col = n0 + wn + ni * 16 + fr;
        float bz = bias[col];
#pragma unroll
        for (int mi = 0; mi < 4; mi++) {
            int row0 = m0 + wm + mi * 16 + rbase;
#pragma unroll
            for (int r = 0; r < 4; r++) {
                int row = row0 + r;
                if (row < M) C[(size_t)row * Nc + col] = acc[mi][ni][r] + bz;
            }
        }
    }
}

// ---------------- edge logits v3 (CSR order) ----------------

__global__ __launch_bounds__(256) void edge_logits3(
        const float* __restrict__ xl, const float* __restrict__ xr,
        const float* __restrict__ We, const float* __restrict__ att,
        const float* __restrict__ ea_csr,
        const int* __restrict__ csr_src, const int* __restrict__ csr_dst,
        float* __restrict__ logits, int H, int co_shift, int hc) {
    __shared__ float sea[128][EDIM];
    __shared__ int ssrc[128], sdst[128];
    int tid = threadIdx.x;
    int lane = tid & 63, wave = tid >> 6;
    int cbase = blockIdx.y * 256;
    int head = cbase >> co_shift;
    int j = cbase + lane * 4;
    int e0 = blockIdx.x * 128;

    for (int t = tid; t < 128 * 4; t += 256) {
        int le = t >> 2, q = t & 3;
        int i = e0 + le;
        float4 v = make_float4(0.f, 0.f, 0.f, 0.f);
        if (i < ETOT) v = *(const float4*)(ea_csr + (size_t)i * EDIM + q * 4);
        *(float4*)&sea[le][q * 4] = v;
    }
    for (int t = tid; t < 128; t += 256) {
        int i = e0 + t;
        ssrc[t] = (i < ETOT) ? csr_src[i] : 0;
        sdst[t] = (i < ETOT) ? csr_dst[i] : 0;
    }
    __syncthreads();

    float4 w[EDIM];
#pragma unroll
    for (int k = 0; k < EDIM; k++)
        w[k] = *(const float4*)(We + (size_t)k * hc + j);
    float4 a4 = *(const float4*)(att + j);

    int lbase = wave * 32;
#pragma unroll 2
    for (int ii = 0; ii < 32; ii++) {
        int le = lbase + ii;
        int i = e0 + le;
        if (i >= ETOT) break;               // wave-uniform
        int s = ssrc[le], d = sdst[le];
        float4 xlv = *(const float4*)(xl + (size_t)s * hc + j);
        float4 xrv = *(const float4*)(xr + (size_t)d * hc + j);
        float4 ee = make_float4(0.f, 0.f, 0.f, 0.f);
#pragma unroll
        for (int k = 0; k < EDIM; k++) {
            float c = sea[le][k];
            ee.x += c * w[k].x; ee.y += c * w[k].y;
            ee.z += c * w[k].z; ee.w += c * w[k].w;
        }
        float mx = xlv.x + xrv.x + ee.x;
        float my = xlv.y + xrv.y + ee.y;
        float mz = xlv.z + xrv.z + ee.z;
        float mw = xlv.w + xrv.w + ee.w;
        mx = (mx > 0.f) ? mx : 0.2f * mx;
        my = (my > 0.f) ? my : 0.2f * my;
        mz = (mz > 0.f) ? mz : 0.2f * mz;
        mw = (mw > 0.f) ? mw : 0.2f * mw;
        float p = mx * a4.x + my * a4.y + mz * a4.z + mw * a4.w;
#pragma unroll
        for (int off = 32; off > 0; off >>= 1)
            p += __shfl_down(p, off, 64);
        if (lane == 0)
            atomicAdd(&logits[(size_t)i * H + head], p);
    }
}

// ---------------- fused softmax + aggregation (CSR-contiguous logits) ----------------

__global__ __launch_bounds__(256) void aggregate3(
        const int* __restrict__ rowptr, const int* __restrict__ csr_src,
        const float* __restrict__ logits, const float* __restrict__ xl,
        const float* __restrict__ bias, float* __restrict__ out,
        int H, int co_shift, int hc) {
    __shared__ int ssrc[64];
    __shared__ float slog[64][4];
    int n = blockIdx.x;
    int b = rowptr[n], t = rowptr[n + 1];
    int j0 = threadIdx.x * 4;
    int j1 = j0 + 1024;
    int h0 = j0 >> co_shift;
    int h1 = j1 >> co_shift;
    bool act0 = j0 < hc, act1 = j1 < hc;

    float m0 = -1e30f, m1 = -1e30f;
    for (int i = b; i < t; i++) {
        if (act0) m0 = fmaxf(m0, logits[(size_t)i * H + h0]);
        if (act1) m1 = fmaxf(m1, logits[(size_t)i * H + h1]);
    }
    float s0 = 0.f, s1 = 0.f;
    for (int i = b; i < t; i++) {
        if (act0) s0 += expf(logits[(size_t)i * H + h0] - m0);
        if (act1) s1 += expf(logits[(size_t)i * H + h1] - m1);
    }
    float inv0 = act0 ? 1.f / s0 : 0.f;
    float inv1 = act1 ? 1.f / s1 : 0.f;

    float4 acc0 = make_float4(0.f, 0.f, 0.f, 0.f);
    float4 acc1 = make_float4(0.f, 0.f, 0.f, 0.f);

    for (int cb = b; cb < t; cb += 64) {
        int m = min(64, t - cb);
        __syncthreads();
        for (int i = threadIdx.x; i < m; i += 256) {
            ssrc[i] = csr_src[cb + i];
            for (int h = 0; h < H; h++)
                slog[i][h] = logits[(size_t)(cb + i) * H + h];
        }
        __syncthreads();
        for (int i = 0; i < m; i++) {
            int s = ssrc[i];
            const float* base = xl + (size_t)s * hc;
            if (act0) {
                float a = expf(slog[i][h0] - m0) * inv0;
                float4 v = *(const float4*)(base + j0);
                acc0.x += a * v.x; acc0.y += a * v.y;
                acc0.z += a * v.z; acc0.w += a * v.w;
            }
            if (act1) {
                float a = expf(slog[i][h1] - m1) * inv1;
                float4 v = *(const float4*)(base + j1);
                acc1.x += a * v.x; acc1.y += a * v.y;
                acc1.z += a * v.z; acc1.w += a * v.w;
            }
        }
    }
    if (act0) {
        float4 bz = *(const float4*)(bias + j0);
        float4 o;
        o.x = fmaxf(acc0.x + bz.x, 0.f); o.y = fmaxf(acc0.y + bz.y, 0.f);
        o.z = fmaxf(acc0.z + bz.z, 0.f); o.w = fmaxf(acc0.w + bz.w, 0.f);
        *(float4*)(out + (size_t)n * hc + j0) = o;
    }
    if (act1) {
        float4 bz = *(const float4*)(bias + j1);
        float4 o;
        o.x = fmaxf(acc1.x + bz.x, 0.f); o.y = fmaxf(acc1.y + bz.y, 0.f);
        o.z = fmaxf(acc1.z + bz.z, 0.f); o.w = fmaxf(acc1.w + bz.w, 0.f);
        *(float4*)(out + (size_t)n * hc + j1) = o;
    }
}

// ---------------- pooling + MLP head ----------------

__global__ void pool_cnt(const int* __restrict__ batch, int* __restrict__ gcnt) {
    int n = blockIdx.x * 256 + threadIdx.x;
    if (n < N_NODES) atomicAdd(&gcnt[batch[n]], 1);
}

__global__ void pool_sum(const int* __restrict__ batch, const float* __restrict__ h,
                         float* __restrict__ pooled) {
    int tid = blockIdx.x * 256 + threadIdx.x;
    if (tid >= N_NODES * 256) return;
    int n = tid >> 8, c = tid & 255;
    atomicAdd(&pooled[batch[n] * 256 + c], h[tid]);
}

__global__ void mlp_head(const float* __restrict__ pooled, const int* __restrict__ gcnt,
                         const float* __restrict__ fc1w, const float* __restrict__ fc1b,
                         const float* __restrict__ fc2w, const float* __restrict__ fc2b,
                         float* __restrict__ out) {
    int g = threadIdx.x;
    if (g >= NGRAPHS) return;
    float inv = 1.f / (float)(gcnt[g] > 0 ? gcnt[g] : 1);
    float s[64];
#pragma unroll
    for (int j = 0; j < 64; j++) s[j] = fc1b[j];
    for (int c = 0; c < 256; c++) {
        float mv = pooled[g * 256 + c] * inv;
#pragma unroll
        for (int j = 0; j < 64; j++) s[j] += mv * fc1w[c * 64 + j];
    }
    float o = 0.f;
#pragma unroll
    for (int j = 0; j < 64; j++) o += fmaxf(s[j], 0.f) * fc2w[j];
    out[g] = o + fc2b[0];
}

// ---------------- launch ----------------

extern "C" void kernel_launch(void* const* d_in, const int* in_sizes, int n_in,
                              void* d_out, int out_size, void* d_ws, size_t ws_size,
                              hipStream_t stream) {
    const float* x         = (const float*)d_in[0];
    const int*   edge_index= (const int*)d_in[1];
    const float* edge_attr = (const float*)d_in[2];
    const int*   batch     = (const int*)d_in[3];
    const int* src0 = edge_index;
    const int* dst0 = edge_index + N_EDGES;

    const float *Wl[4], *bl[4], *Wr[4], *br[4], *We[4], *att[4], *bias[4];
    for (int i = 0; i < 4; i++) {
        int base = 4 + 7 * i;
        Wl[i]   = (const float*)d_in[base + 0];
        bl[i]   = (const float*)d_in[base + 1];
        Wr[i]   = (const float*)d_in[base + 2];
        br[i]   = (const float*)d_in[base + 3];
        We[i]   = (const float*)d_in[base + 4];
        att[i]  = (const float*)d_in[base + 5];
        bias[i] = (const float*)d_in[base + 6];
    }
    const float* fc1w = (const float*)d_in[32];
    const float* fc1b = (const float*)d_in[33];
    const float* fc2w = (const float*)d_in[34];
    const float* fc2b = (const float*)d_in[35];
    float* out = (float*)d_out;

    float* ws = (float*)d_ws;
    int*   rowptr  = (int*)(ws + 0);            // 8001
    int*   woff    = (int*)(ws + 8064);         // 8000
    int*   eid     = (int*)(ws + 16128);        // 72000
    int*   csr_src = (int*)(ws + 88128);        // 72000
    int*   csr_dst = (int*)(ws + 160128);       // 72000
    float* ea_loop = ws + 232128;               // 8000*16
    float* ea_csr  = ws + 360128;               // 72000*16
    float* logits  = ws + 1512128;              // 72000*3
    float* xl      = ws + 1728128;              // 8000*1536
    float* xr      = xl  + 12288000;
    float* hb0     = xr  + 12288000;            // 8000*1536 (L1, L3 out)
    float* hb1     = hb0 + 12288000;            // 8000*1024 (L2, L4 out)
    float* pooled  = hb1 + 8192000;             // 64*256
    int*   gcnt    = (int*)(pooled + 16384);    // 64
    // wth/wtl each need 1536*1536 shorts = 1179648 floats — keep them DISJOINT
    short* wth     = (short*)(ws + 46800576);   // ends at 47980224 floats
    short* wtl     = (short*)(ws + 47980224);   // ends at 49159872 floats (~197 MB)

    hipMemsetAsync(woff, 0, N_NODES * sizeof(int), stream);
    count_deg<<<(N_EDGES + 255) / 256, 256, 0, stream>>>(dst0, woff);
    scan_deg<<<1, 256, 0, stream>>>(woff, rowptr);
    copy_off<<<(N_NODES + 255) / 256, 256, 0, stream>>>(rowptr, woff);
    fill_eid<<<(ETOT + 255) / 256, 256, 0, stream>>>(dst0, woff, eid);
    csr_fill_dst<<<(N_NODES + 255) / 256, 256, 0, stream>>>(rowptr, csr_dst);
    ea_loop_kernel<<<(N_NODES + 255) / 256, 256, 0, stream>>>(rowptr, eid, edge_attr, ea_loop);
    csr_srcea<<<(ETOT * 4 + 255) / 256, 256, 0, stream>>>(eid, src0, edge_attr, ea_loop,
                                                          csr_src, ea_csr);

    const int IN[4] = {256, 1536, 1024, 512};
    const int HH[4] = {3, 2, 2, 1};
    const int CO[4] = {512, 512, 256, 256};
    const int CS[4] = {9, 9, 8, 8};            // log2(co)
    const float* hin = x;
    float* houts[4] = {hb0, hb1, hb0, hb1};

    for (int L = 0; L < 4; L++) {
        int K = IN[L], H = HH[L], co = CO[L], hc = H * co, cs = CS[L];
        (void)co;
        dim3 gg(hc / 128, (N_NODES + 127) / 128);
        dim3 gw(hc / 32, K / 32);
        cvt_wt_t<<<gw, 256, 0, stream>>>(Wl[L], wth, wtl, K, hc);
        gemm_mfma<<<gg, 256, 0, stream>>>(hin, wth, wtl, bl[L], xl, N_NODES, K, hc);
        cvt_wt_t<<<gw, 256, 0, stream>>>(Wr[L], wth, wtl, K, hc);
        gemm_mfma<<<gg, 256, 0, stream>>>(hin, wth, wtl, br[L], xr, N_NODES, K, hc);
        hipMemsetAsync(logits, 0, (size_t)ETOT * H * sizeof(float), stream);
        dim3 gl((ETOT + 127) / 128, hc / 256);
        edge_logits3<<<gl, 256, 0, stream>>>(
            xl, xr, We[L], att[L], ea_csr, csr_src, csr_dst, logits, H, cs, hc);
        aggregate3<<<N_NODES, 256, 0, stream>>>(
            rowptr, csr_src, logits, xl, bias[L], houts[L], H, cs, hc);
        hin = houts[L];
    }

    hipMemsetAsync(pooled, 0, (16384 + 64) * sizeof(float), stream);
    pool_cnt<<<(N_NODES + 255) / 256, 256, 0, stream>>>(batch, gcnt);
    pool_sum<<<(N_NODES * 256 + 255) / 256, 256, 0, stream>>>(batch, hin, pooled);
    mlp_head<<<1, 64, 0, stream>>>(pooled, gcnt, fc1w, fc1b, fc2w, fc2b, out);
}

// Round 7
// 1492.017 us; speedup vs baseline: 1.8331x; 1.0475x over previous
//
#include <hip/hip_runtime.h>
#include <math.h>

#define N_NODES 8000
#define N_EDGES 64000
#define ETOT    (N_EDGES + N_NODES)   // 72000, self-loops appended
#define EDIM    16
#define NGRAPHS 64

typedef __attribute__((ext_vector_type(8))) short short8v;
typedef __attribute__((ext_vector_type(4))) short short4v;
typedef __attribute__((ext_vector_type(4))) float f32x4;

__device__ inline unsigned short f2bf(float f) {
    unsigned u = __builtin_bit_cast(unsigned, f);
    unsigned r = (u + 0x7FFF + ((u >> 16) & 1)) >> 16;   // RNE
    return (unsigned short)r;
}
__device__ inline float bf2f(unsigned short b) {
    unsigned u = ((unsigned)b) << 16;
    return __builtin_bit_cast(float, u);
}

// ---------------- CSR build ----------------

__global__ void count_deg(const int* __restrict__ dst0, int* __restrict__ deg) {
    int e = blockIdx.x * 256 + threadIdx.x;
    if (e < N_EDGES) atomicAdd(&deg[dst0[e]], 1);
}

__global__ void scan_deg(const int* __restrict__ deg, int* __restrict__ rowptr) {
    __shared__ int sh[256];
    __shared__ int carry_s;
    int t = threadIdx.x;
    if (t == 0) { carry_s = 0; rowptr[0] = 0; }
    __syncthreads();
    for (int base = 0; base < N_NODES; base += 256) {
        int i = base + t;
        int v = (i < N_NODES) ? (deg[i] + 1) : 0;   // +1 self loop
        sh[t] = v;
        __syncthreads();
        for (int off = 1; off < 256; off <<= 1) {
            int u = (t >= off) ? sh[t - off] : 0;
            __syncthreads();
            sh[t] += u;
            __syncthreads();
        }
        int incl = sh[t] + carry_s;
        if (i < N_NODES) rowptr[i + 1] = incl;
        __syncthreads();
        if (t == 255) carry_s = incl;
        __syncthreads();
    }
}

__global__ void copy_off(const int* __restrict__ rowptr, int* __restrict__ woff) {
    int i = blockIdx.x * 256 + threadIdx.x;
    if (i < N_NODES) woff[i] = rowptr[i];
}

__global__ void fill_eid(const int* __restrict__ dst0, int* __restrict__ woff,
                         int* __restrict__ eid) {
    int i = blockIdx.x * 256 + threadIdx.x;
    if (i < N_EDGES) {
        int pos = atomicAdd(&woff[dst0[i]], 1);
        eid[pos] = i;
    } else if (i < ETOT) {
        int n = i - N_EDGES;
        int pos = atomicAdd(&woff[n], 1);
        eid[pos] = i;
    }
}

__global__ void csr_fill_dst(const int* __restrict__ rowptr, int* __restrict__ csr_dst) {
    int n = blockIdx.x * 256 + threadIdx.x;
    if (n >= N_NODES) return;
    int b = rowptr[n], t = rowptr[n + 1];
    for (int i = b; i < t; i++) csr_dst[i] = n;
}

__global__ void ea_loop_kernel(const int* __restrict__ rowptr, const int* __restrict__ eid,
                               const float* __restrict__ edge_attr, float* __restrict__ ea_loop) {
    int n = blockIdx.x * 256 + threadIdx.x;
    if (n >= N_NODES) return;
    float s[EDIM];
#pragma unroll
    for (int k = 0; k < EDIM; k++) s[k] = 0.f;
    int cnt = 0;
    int b = rowptr[n], t = rowptr[n + 1];
    for (int i = b; i < t; i++) {
        int e = eid[i];
        if (e < N_EDGES) {
            cnt++;
            const float* ea = edge_attr + (size_t)e * EDIM;
#pragma unroll
            for (int k = 0; k < EDIM; k++) s[k] += ea[k];
        }
    }
    float inv = 1.f / (float)(cnt > 0 ? cnt : 1);
#pragma unroll
    for (int k = 0; k < EDIM; k++) ea_loop[(size_t)n * EDIM + k] = s[k] * inv;
}

__global__ void csr_srcea(const int* __restrict__ eid, const int* __restrict__ src0,
                          const float* __restrict__ edge_attr, const float* __restrict__ ea_loop,
                          int* __restrict__ csr_src, float* __restrict__ ea_csr) {
    int t = blockIdx.x * 256 + threadIdx.x;
    int i = t >> 2, q = t & 3;
    if (i >= ETOT) return;
    int e = eid[i];
    int s = (e < N_EDGES) ? src0[e] : (e - N_EDGES);
    if (q == 0) csr_src[i] = s;
    const float* ea = (e < N_EDGES) ? edge_attr + (size_t)e * EDIM
                                    : ea_loop + (size_t)(e - N_EDGES) * EDIM;
    *(float4*)(ea_csr + (size_t)i * EDIM + q * 4) = *(const float4*)(ea + q * 4);
}

// ---------------- weight transpose + bf16 split: W[K][N] -> WT_hi/lo[N][K] ----------------

__global__ __launch_bounds__(256) void cvt_wt_t(
        const float* __restrict__ W, short* __restrict__ WTh, short* __restrict__ WTl,
        int K, int Nc) {
    __shared__ float sh[32][33];
    int t = threadIdx.x;
    int tx = t & 31, ty = t >> 5;            // 32 x 8
    int n0 = blockIdx.x * 32, k0 = blockIdx.y * 32;
#pragma unroll
    for (int j = 0; j < 4; j++)
        sh[ty + j * 8][tx] = W[(size_t)(k0 + ty + j * 8) * Nc + n0 + tx];
    __syncthreads();
#pragma unroll
    for (int j = 0; j < 4; j++) {
        int row = ty + j * 8;                 // local n
        float v = sh[tx][row];
        unsigned short h = f2bf(v);
        unsigned short l = f2bf(v - bf2f(h));
        size_t idx = (size_t)(n0 + row) * K + k0 + tx;
        WTh[idx] = (short)h;
        WTl[idx] = (short)l;
    }
}

// ---------------- activation bf16 hi/lo pre-split (row-major [M x K]) ----------------

__global__ __launch_bounds__(256) void cvt_act(
        const float* __restrict__ in, short* __restrict__ acth, short* __restrict__ actl,
        int total /* M*K, multiple of 4 */) {
    int i = blockIdx.x * 256 + threadIdx.x;
    if (i * 4 >= total) return;
    float4 v = *(const float4*)(in + (size_t)i * 4);
    unsigned short h0 = f2bf(v.x), h1 = f2bf(v.y), h2 = f2bf(v.z), h3 = f2bf(v.w);
    short4v hv = { (short)h0, (short)h1, (short)h2, (short)h3 };
    short4v lv = { (short)f2bf(v.x - bf2f(h0)), (short)f2bf(v.y - bf2f(h1)),
                   (short)f2bf(v.z - bf2f(h2)), (short)f2bf(v.w - bf2f(h3)) };
    *(short4v*)(acth + (size_t)i * 4) = hv;
    *(short4v*)(actl + (size_t)i * 4) = lv;
}

// ---------------- bf16x3 MFMA GEMM, A pre-split variant ----------------
// A_hi/lo bf16 row-major [M x K] (padded to 8064 rows); BT_hi/lo bf16 [Nc][K].

#define LDK 40   // padded LDS row stride in shorts (32 + 8)

__global__ __launch_bounds__(256) void gemm_mfma2(
        const short* __restrict__ Ah_g, const short* __restrict__ Al_g,
        const short* __restrict__ BTh, const short* __restrict__ BTl,
        const float* __restrict__ bias, float* __restrict__ C,
        int M, int K, int Nc) {
    __shared__ short Ah[128 * LDK];
    __shared__ short Al[128 * LDK];
    __shared__ short Bh[128 * LDK];
    __shared__ short Bl[128 * LDK];
    int t = threadIdx.x;
    int m0 = blockIdx.y * 128, n0 = blockIdx.x * 128;
    int lane = t & 63, wave = t >> 6;
    int wm = (wave >> 1) * 64, wn = (wave & 1) * 64;
    int fr = lane & 15, koff = (lane >> 4) * 8;

    f32x4 acc[4][4];
#pragma unroll
    for (int i = 0; i < 4; i++)
#pragma unroll
        for (int j = 0; j < 4; j++) acc[i][j] = (f32x4)(0.f);

    int srow = t >> 1, sseg = t & 1;          // one 16-short (32B) chunk per thread

    for (int k0 = 0; k0 < K; k0 += 32) {
        __syncthreads();
        {
            const short* ga_h = Ah_g + (size_t)(m0 + srow) * K + k0 + sseg * 16;
            const short* ga_l = Al_g + (size_t)(m0 + srow) * K + k0 + sseg * 16;
            const short* gb_h = BTh + (size_t)(n0 + srow) * K + k0 + sseg * 16;
            const short* gb_l = BTl + (size_t)(n0 + srow) * K + k0 + sseg * 16;
            int lo = srow * LDK + sseg * 16;
            *(short8v*)&Ah[lo]     = *(const short8v*)ga_h;
            *(short8v*)&Ah[lo + 8] = *(const short8v*)(ga_h + 8);
            *(short8v*)&Al[lo]     = *(const short8v*)ga_l;
            *(short8v*)&Al[lo + 8] = *(const short8v*)(ga_l + 8);
            *(short8v*)&Bh[lo]     = *(const short8v*)gb_h;
            *(short8v*)&Bh[lo + 8] = *(const short8v*)(gb_h + 8);
            *(short8v*)&Bl[lo]     = *(const short8v*)gb_l;
            *(short8v*)&Bl[lo + 8] = *(const short8v*)(gb_l + 8);
        }
        __syncthreads();

        short8v ah[4], al[4], bh[4], bl[4];
#pragma unroll
        for (int mi = 0; mi < 4; mi++) {
            int r = (wm + mi * 16 + fr) * LDK + koff;
            ah[mi] = *(short8v*)&Ah[r];
            al[mi] = *(short8v*)&Al[r];
        }
#pragma unroll
        for (int ni = 0; ni < 4; ni++) {
            int r = (wn + ni * 16 + fr) * LDK + koff;
            bh[ni] = *(short8v*)&Bh[r];
            bl[ni] = *(short8v*)&Bl[r];
        }
#pragma unroll
        for (int mi = 0; mi < 4; mi++)
#pragma unroll
            for (int ni = 0; ni < 4; ni++) {
                acc[mi][ni] = __builtin_amdgcn_mfma_f32_16x16x32_bf16(
                    al[mi], bh[ni], acc[mi][ni], 0, 0, 0);
                acc[mi][ni] = __builtin_amdgcn_mfma_f32_16x16x32_bf16(
                    ah[mi], bl[ni], acc[mi][ni], 0, 0, 0);
                acc[mi][ni] = __builtin_amdgcn_mfma_f32_16x16x32_bf16(
                    ah[mi], bh[ni], acc[mi][ni], 0, 0, 0);
            }
    }

    int rbase = (lane >> 4) * 4;
#pragma unroll
    for (int ni = 0; ni < 4; ni++) {
        int col = n0 + wn + ni * 16 + fr;
        float bz = bias[col];
#pragma unroll
        for (int mi = 0; mi < 4; mi++) {
            int row0 = m0 + wm + mi * 16 + rbase;
#pragma unroll
            for (int r = 0; r < 4; r++) {
                int row = row0 + r;
                if (row < M) C[(size_t)row * Nc + col] = acc[mi][ni][r] + bz;
            }
        }
    }
}

// ---------------- bf16x3 MFMA GEMM, fp32-A fallback (in-kernel split) ----------------

__global__ __launch_bounds__(256) void gemm_mfma(
        const float* __restrict__ A, const short* __restrict__ BTh,
        const short* __restrict__ BTl, const float* __restrict__ bias,
        float* __restrict__ C, int M, int K, int Nc) {
    __shared__ short Ah[128 * LDK];
    __shared__ short Al[128 * LDK];
    __shared__ short Bh[128 * LDK];
    __shared__ short Bl[128 * LDK];
    int t = threadIdx.x;
    int m0 = blockIdx.y * 128, n0 = blockIdx.x * 128;
    int lane = t & 63, wave = t >> 6;
    int wm = (wave >> 1) * 64, wn = (wave & 1) * 64;
    int fr = lane & 15, koff = (lane >> 4) * 8;

    f32x4 acc[4][4];
#pragma unroll
    for (int i = 0; i < 4; i++)
#pragma unroll
        for (int j = 0; j < 4; j++) acc[i][j] = (f32x4)(0.f);

    int brow = t >> 1, bseg = t & 1;

    for (int k0 = 0; k0 < K; k0 += 32) {
        __syncthreads();
#pragma unroll
        for (int i = 0; i < 4; i++) {
            int f = t + i * 256;
            int row = f >> 3, seg = f & 7;
            float4 v = make_float4(0.f, 0.f, 0.f, 0.f);
            if (m0 + row < M)
                v = *(const float4*)(A + (size_t)(m0 + row) * K + k0 + seg * 4);
            unsigned short h0 = f2bf(v.x), h1 = f2bf(v.y), h2 = f2bf(v.z), h3 = f2bf(v.w);
            short4v hv = { (short)h0, (short)h1, (short)h2, (short)h3 };
            short4v lv = { (short)f2bf(v.x - bf2f(h0)), (short)f2bf(v.y - bf2f(h1)),
                           (short)f2bf(v.z - bf2f(h2)), (short)f2bf(v.w - bf2f(h3)) };
            *(short4v*)&Ah[row * LDK + seg * 4] = hv;
            *(short4v*)&Al[row * LDK + seg * 4] = lv;
        }
        {
            const short* gh = BTh + (size_t)(n0 + brow) * K + k0 + bseg * 16;
            const short* gl = BTl + (size_t)(n0 + brow) * K + k0 + bseg * 16;
            int lo = brow * LDK + bseg * 16;
            *(short8v*)&Bh[lo]     = *(const short8v*)gh;
            *(short8v*)&Bh[lo + 8] = *(const short8v*)(gh + 8);
            *(short8v*)&Bl[lo]     = *(const short8v*)gl;
            *(short8v*)&Bl[lo + 8] = *(const short8v*)(gl + 8);
        }
        __syncthreads();

        short8v ah[4], al[4], bh[4], bl[4];
#pragma unroll
        for (int mi = 0; mi < 4; mi++) {
            int r = (wm + mi * 16 + fr) * LDK + koff;
            ah[mi] = *(short8v*)&Ah[r];
            al[mi] = *(short8v*)&Al[r];
        }
#pragma unroll
        for (int ni = 0; ni < 4; ni++) {
            int r = (wn + ni * 16 + fr) * LDK + koff;
            bh[ni] = *(short8v*)&Bh[r];
            bl[ni] = *(short8v*)&Bl[r];
        }
#pragma unroll
        for (int mi = 0; mi < 4; mi++)
#pragma unroll
            for (int ni = 0; ni < 4; ni++) {
                acc[mi][ni] = __builtin_amdgcn_mfma_f32_16x16x32_bf16(
                    al[mi], bh[ni], acc[mi][ni], 0, 0, 0);
                acc[mi][ni] = __builtin_amdgcn_mfma_f32_16x16x32_bf16(
                    ah[mi], bl[ni], acc[mi][ni], 0, 0, 0);
                acc[mi][ni] = __builtin_amdgcn_mfma_f32_16x16x32_bf16(
                    ah[mi], bh[ni], acc[mi][ni], 0, 0, 0);
            }
    }

    int rbase = (lane >> 4) * 4;
#pragma unroll
    for (int ni = 0; ni < 4; ni++) {
        int col = n0 + wn + ni * 16 + fr;
        float bz = bias[col];
#pragma unroll
        for (int mi = 0; mi < 4; mi++) {
            int row0 = m0 + wm + mi * 16 + rbase;
#pragma unroll
            for (int r = 0; r < 4; r++) {
                int row = row0 + r;
                if (row < M) C[(size_t)row * Nc + col] = acc[mi][ni][r] + bz;
            }
        }
    }
}

// ---------------- edge logits v3 (CSR order) ----------------

__global__ __launch_bounds__(256) void edge_logits3(
        const float* __restrict__ xl, const float* __restrict__ xr,
        const float* __restrict__ We, const float* __restrict__ att,
        const float* __restrict__ ea_csr,
        const int* __restrict__ csr_src, const int* __restrict__ csr_dst,
        float* __restrict__ logits, int H, int co_shift, int hc) {
    __shared__ float sea[128][EDIM];
    __shared__ int ssrc[128], sdst[128];
    int tid = threadIdx.x;
    int lane = tid & 63, wave = tid >> 6;
    int cbase = blockIdx.y * 256;
    int head = cbase >> co_shift;
    int j = cbase + lane * 4;
    int e0 = blockIdx.x * 128;

    for (int t = tid; t < 128 * 4; t += 256) {
        int le = t >> 2, q = t & 3;
        int i = e0 + le;
        float4 v = make_float4(0.f, 0.f, 0.f, 0.f);
        if (i < ETOT) v = *(const float4*)(ea_csr + (size_t)i * EDIM + q * 4);
        *(float4*)&sea[le][q * 4] = v;
    }
    for (int t = tid; t < 128; t += 256) {
        int i = e0 + t;
        ssrc[t] = (i < ETOT) ? csr_src[i] : 0;
        sdst[t] = (i < ETOT) ? csr_dst[i] : 0;
    }
    __syncthreads();

    float4 w[EDIM];
#pragma unroll
    for (int k = 0; k < EDIM; k++)
        w[k] = *(const float4*)(We + (size_t)k * hc + j);
    float4 a4 = *(const float4*)(att + j);

    int lbase = wave * 32;
#pragma unroll 2
    for (int ii = 0; ii < 32; ii++) {
        int le = lbase + ii;
        int i = e0 + le;
        if (i >= ETOT) break;               // wave-uniform
        int s = ssrc[le], d = sdst[le];
        float4 xlv = *(const float4*)(xl + (size_t)s * hc + j);
        float4 xrv = *(const float4*)(xr + (size_t)d * hc + j);
        // ea as 4 x float4 LDS reads (b128)
        float eav[EDIM];
        *(float4*)&eav[0]  = *(float4*)&sea[le][0];
        *(float4*)&eav[4]  = *(float4*)&sea[le][4];
        *(float4*)&eav[8]  = *(float4*)&sea[le][8];
        *(float4*)&eav[12] = *(float4*)&sea[le][12];
        float4 ee = make_float4(0.f, 0.f, 0.f, 0.f);
#pragma unroll
        for (int k = 0; k < EDIM; k++) {
            float c = eav[k];
            ee.x += c * w[k].x; ee.y += c * w[k].y;
            ee.z += c * w[k].z; ee.w += c * w[k].w;
        }
        float mx = xlv.x + xrv.x + ee.x;
        float my = xlv.y + xrv.y + ee.y;
        float mz = xlv.z + xrv.z + ee.z;
        float mw = xlv.w + xrv.w + ee.w;
        mx = (mx > 0.f) ? mx : 0.2f * mx;
        my = (my > 0.f) ? my : 0.2f * my;
        mz = (mz > 0.f) ? mz : 0.2f * mz;
        mw = (mw > 0.f) ? mw : 0.2f * mw;
        float p = mx * a4.x + my * a4.y + mz * a4.z + mw * a4.w;
#pragma unroll
        for (int off = 32; off > 0; off >>= 1)
            p += __shfl_down(p, off, 64);
        if (lane == 0)
            atomicAdd(&logits[(size_t)i * H + head], p);
    }
}

// ---------------- fused softmax + aggregation (CSR-contiguous logits) ----------------

__global__ __launch_bounds__(256) void aggregate3(
        const int* __restrict__ rowptr, const int* __restrict__ csr_src,
        const float* __restrict__ logits, const float* __restrict__ xl,
        const float* __restrict__ bias, float* __restrict__ out,
        int H, int co_shift, int hc) {
    __shared__ int ssrc[64];
    __shared__ float slog[64][4];
    int n = blockIdx.x;
    int b = rowptr[n], t = rowptr[n + 1];
    int j0 = threadIdx.x * 4;
    int j1 = j0 + 1024;
    int h0 = j0 >> co_shift;
    int h1 = j1 >> co_shift;
    bool act0 = j0 < hc, act1 = j1 < hc;

    float m0 = -1e30f, m1 = -1e30f;
    for (int i = b; i < t; i++) {
        if (act0) m0 = fmaxf(m0, logits[(size_t)i * H + h0]);
        if (act1) m1 = fmaxf(m1, logits[(size_t)i * H + h1]);
    }
    float s0 = 0.f, s1 = 0.f;
    for (int i = b; i < t; i++) {
        if (act0) s0 += expf(logits[(size_t)i * H + h0] - m0);
        if (act1) s1 += expf(logits[(size_t)i * H + h1] - m1);
    }
    float inv0 = act0 ? 1.f / s0 : 0.f;
    float inv1 = act1 ? 1.f / s1 : 0.f;

    float4 acc0 = make_float4(0.f, 0.f, 0.f, 0.f);
    float4 acc1 = make_float4(0.f, 0.f, 0.f, 0.f);

    for (int cb = b; cb < t; cb += 64) {
        int m = min(64, t - cb);
        __syncthreads();
        for (int i = threadIdx.x; i < m; i += 256) {
            ssrc[i] = csr_src[cb + i];
            for (int h = 0; h < H; h++)
                slog[i][h] = logits[(size_t)(cb + i) * H + h];
        }
        __syncthreads();
        for (int i = 0; i < m; i++) {
            int s = ssrc[i];
            const float* base = xl + (size_t)s * hc;
            if (act0) {
                float a = expf(slog[i][h0] - m0) * inv0;
                float4 v = *(const float4*)(base + j0);
                acc0.x += a * v.x; acc0.y += a * v.y;
                acc0.z += a * v.z; acc0.w += a * v.w;
            }
            if (act1) {
                float a = expf(slog[i][h1] - m1) * inv1;
                float4 v = *(const float4*)(base + j1);
                acc1.x += a * v.x; acc1.y += a * v.y;
                acc1.z += a * v.z; acc1.w += a * v.w;
            }
        }
    }
    if (act0) {
        float4 bz = *(const float4*)(bias + j0);
        float4 o;
        o.x = fmaxf(acc0.x + bz.x, 0.f); o.y = fmaxf(acc0.y + bz.y, 0.f);
        o.z = fmaxf(acc0.z + bz.z, 0.f); o.w = fmaxf(acc0.w + bz.w, 0.f);
        *(float4*)(out + (size_t)n * hc + j0) = o;
    }
    if (act1) {
        float4 bz = *(const float4*)(bias + j1);
        float4 o;
        o.x = fmaxf(acc1.x + bz.x, 0.f); o.y = fmaxf(acc1.y + bz.y, 0.f);
        o.z = fmaxf(acc1.z + bz.z, 0.f); o.w = fmaxf(acc1.w + bz.w, 0.f);
        *(float4*)(out + (size_t)n * hc + j1) = o;
    }
}

// ---------------- pooling + MLP head ----------------

__global__ void pool_cnt(const int* __restrict__ batch, int* __restrict__ gcnt) {
    int n = blockIdx.x * 256 + threadIdx.x;
    if (n < N_NODES) atomicAdd(&gcnt[batch[n]], 1);
}

__global__ void pool_sum(const int* __restrict__ batch, const float* __restrict__ h,
                         float* __restrict__ pooled) {
    int tid = blockIdx.x * 256 + threadIdx.x;
    if (tid >= N_NODES * 256) return;
    int n = tid >> 8, c = tid & 255;
    atomicAdd(&pooled[batch[n] * 256 + c], h[tid]);
}

__global__ void mlp_head(const float* __restrict__ pooled, const int* __restrict__ gcnt,
                         const float* __restrict__ fc1w, const float* __restrict__ fc1b,
                         const float* __restrict__ fc2w, const float* __restrict__ fc2b,
                         float* __restrict__ out) {
    int g = threadIdx.x;
    if (g >= NGRAPHS) return;
    float inv = 1.f / (float)(gcnt[g] > 0 ? gcnt[g] : 1);
    float s[64];
#pragma unroll
    for (int j = 0; j < 64; j++) s[j] = fc1b[j];
    for (int c = 0; c < 256; c++) {
        float mv = pooled[g * 256 + c] * inv;
#pragma unroll
        for (int j = 0; j < 64; j++) s[j] += mv * fc1w[c * 64 + j];
    }
    float o = 0.f;
#pragma unroll
    for (int j = 0; j < 64; j++) o += fmaxf(s[j], 0.f) * fc2w[j];
    out[g] = o + fc2b[0];
}

// ---------------- launch ----------------

extern "C" void kernel_launch(void* const* d_in, const int* in_sizes, int n_in,
                              void* d_out, int out_size, void* d_ws, size_t ws_size,
                              hipStream_t stream) {
    const float* x         = (const float*)d_in[0];
    const int*   edge_index= (const int*)d_in[1];
    const float* edge_attr = (const float*)d_in[2];
    const int*   batch     = (const int*)d_in[3];
    const int* src0 = edge_index;
    const int* dst0 = edge_index + N_EDGES;

    const float *Wl[4], *bl[4], *Wr[4], *br[4], *We[4], *att[4], *bias[4];
    for (int i = 0; i < 4; i++) {
        int base = 4 + 7 * i;
        Wl[i]   = (const float*)d_in[base + 0];
        bl[i]   = (const float*)d_in[base + 1];
        Wr[i]   = (const float*)d_in[base + 2];
        br[i]   = (const float*)d_in[base + 3];
        We[i]   = (const float*)d_in[base + 4];
        att[i]  = (const float*)d_in[base + 5];
        bias[i] = (const float*)d_in[base + 6];
    }
    const float* fc1w = (const float*)d_in[32];
    const float* fc1b = (const float*)d_in[33];
    const float* fc2w = (const float*)d_in[34];
    const float* fc2b = (const float*)d_in[35];
    float* out = (float*)d_out;

    // workspace layout (float offsets)
    float* ws = (float*)d_ws;
    int*   rowptr  = (int*)(ws + 0);            // 8001
    int*   woff    = (int*)(ws + 8064);         // 8000
    int*   eid     = (int*)(ws + 16128);        // 72000
    int*   csr_src = (int*)(ws + 88128);        // 72000
    int*   csr_dst = (int*)(ws + 160128);       // 72000
    float* ea_loop = ws + 232128;               // 8000*16
    float* ea_csr  = ws + 360128;               // 72000*16
    float* logits  = ws + 1512128;              // 72000*3
    float* xl      = ws + 1728128;              // 8000*1536
    float* xr      = xl  + 12288000;            // 8000*1536
    float* hbF     = xr  + 12288000;            // 8000*1536 fp32 activations (single buffer:
                                                // hin is dead after cvt_act, hout reuses it)
    float* pooled  = hbF + 12288000;            // 64*256   -> offset 38592128
    int*   gcnt    = (int*)(pooled + 16384);    // 64
    short* wth     = (short*)(ws + 38608640);   // 1536*1536 shorts = 1179648 floats
    short* wtl     = (short*)(ws + 39788288);   // 1179648 floats -> ends 40967936
    short* acth    = (short*)(ws + 40967936);   // 8064*1536 shorts = 6193152 floats (row-padded)
    short* actl    = (short*)(ws + 47161088);   // 6193152 floats -> ends 53354240
    const size_t NEED_PRESPLIT = (size_t)53354240 * 4;
    bool presplit = ws_size >= NEED_PRESPLIT;

    hipMemsetAsync(woff, 0, N_NODES * sizeof(int), stream);
    count_deg<<<(N_EDGES + 255) / 256, 256, 0, stream>>>(dst0, woff);
    scan_deg<<<1, 256, 0, stream>>>(woff, rowptr);
    copy_off<<<(N_NODES + 255) / 256, 256, 0, stream>>>(rowptr, woff);
    fill_eid<<<(ETOT + 255) / 256, 256, 0, stream>>>(dst0, woff, eid);
    csr_fill_dst<<<(N_NODES + 255) / 256, 256, 0, stream>>>(rowptr, csr_dst);
    ea_loop_kernel<<<(N_NODES + 255) / 256, 256, 0, stream>>>(rowptr, eid, edge_attr, ea_loop);
    csr_srcea<<<(ETOT * 4 + 255) / 256, 256, 0, stream>>>(eid, src0, edge_attr, ea_loop,
                                                          csr_src, ea_csr);

    const int IN[4] = {256, 1536, 1024, 512};
    const int HH[4] = {3, 2, 2, 1};
    const int CO[4] = {512, 512, 256, 256};
    const int CS[4] = {9, 9, 8, 8};            // log2(co)
    const float* hin = x;

    for (int L = 0; L < 4; L++) {
        int K = IN[L], H = HH[L], co = CO[L], hc = H * co, cs = CS[L];
        (void)co;
        dim3 gg(hc / 128, (N_NODES + 127) / 128);
        dim3 gw(hc / 32, K / 32);
        if (presplit) {
            int total = N_NODES * K;
            cvt_act<<<(total / 4 + 255) / 256, 256, 0, stream>>>(hin, acth, actl, total);
            cvt_wt_t<<<gw, 256, 0, stream>>>(Wl[L], wth, wtl, K, hc);
            gemm_mfma2<<<gg, 256, 0, stream>>>(acth, actl, wth, wtl, bl[L], xl, N_NODES, K, hc);
            cvt_wt_t<<<gw, 256, 0, stream>>>(Wr[L], wth, wtl, K, hc);
            gemm_mfma2<<<gg, 256, 0, stream>>>(acth, actl, wth, wtl, br[L], xr, N_NODES, K, hc);
        } else {
            cvt_wt_t<<<gw, 256, 0, stream>>>(Wl[L], wth, wtl, K, hc);
            gemm_mfma<<<gg, 256, 0, stream>>>(hin, wth, wtl, bl[L], xl, N_NODES, K, hc);
            cvt_wt_t<<<gw, 256, 0, stream>>>(Wr[L], wth, wtl, K, hc);
            gemm_mfma<<<gg, 256, 0, stream>>>(hin, wth, wtl, br[L], xr, N_NODES, K, hc);
        }
        hipMemsetAsync(logits, 0, (size_t)ETOT * H * sizeof(float), stream);
        dim3 gl((ETOT + 127) / 128, hc / 256);
        edge_logits3<<<gl, 256, 0, stream>>>(
            xl, xr, We[L], att[L], ea_csr, csr_src, csr_dst, logits, H, cs, hc);
        aggregate3<<<N_NODES, 256, 0, stream>>>(
            rowptr, csr_src, logits, xl, bias[L], hbF, H, cs, hc);
        hin = hbF;
    }

    hipMemsetAsync(pooled, 0, (16384 + 64) * sizeof(float), stream);
    pool_cnt<<<(N_NODES + 255) / 256, 256, 0, stream>>>(batch, gcnt);
    pool_sum<<<(N_NODES * 256 + 255) / 256, 256, 0, stream>>>(batch, hbF, pooled);
    mlp_head<<<1, 64, 0, stream>>>(pooled, gcnt, fc1w, fc1b, fc2w, fc2b, out);
}